// Round 1
// baseline (1356.382 us; speedup 1.0000x reference)
//
#include <hip/hip_runtime.h>
#include <cstdint>
#include <cstddef>

#define BT 256              // threads in nms kernel
#define NBINS 65536         // 16-bit histogram of orderable score
#define CAP_SORT 2048       // bitonic sort size (pow2)
#define CAP_C 1536          // max candidates per chunk
#define TARGET 1280u        // chunk selection target
#define KMAX 1008           // kept-list LDS capacity

__device__ __forceinline__ unsigned orderable(float f) {
  unsigned b = __float_as_uint(f);
  return (b & 0x80000000u) ? ~b : (b | 0x80000000u);
}

__global__ void init_kernel(unsigned* __restrict__ hist, int histN,
                            float* __restrict__ out, int outN) {
  int i = blockIdx.x * blockDim.x + threadIdx.x;
  int stride = gridDim.x * blockDim.x;
  for (int j = i; j < histN; j += stride) hist[j] = 0u;
  for (int j = i; j < outN; j += stride) out[j] = 0.0f;
}

__global__ void decode_kernel(const float4* __restrict__ anchors,
                              const float4* __restrict__ deltas,
                              const float* __restrict__ obj,
                              const int* __restrict__ im_h_p,
                              const int* __restrict__ im_w_p,
                              float4* __restrict__ boxes,
                              unsigned* __restrict__ keys,
                              unsigned* __restrict__ hist,
                              int N, int B) {
#pragma clang fp contract(off)
  int n = blockIdx.x * blockDim.x + threadIdx.x;
  if (n >= N) return;
  float imw = (float)(*im_w_p);
  float imh = (float)(*im_h_p);
  float4 a = anchors[n];
  float aw = a.z - a.x;
  float ah = a.w - a.y;
  float acx = a.x + 0.5f * aw;
  float acy = a.y + 0.5f * ah;
  const float LOGM = 4.135166556742356f;  // log(1000/16) rounded to f32
  for (int b = 0; b < B; ++b) {
    size_t off = (size_t)b * N + n;
    float4 d = deltas[off];
    float dw = fminf(d.z, LOGM), dh = fminf(d.w, LOGM);
    float pcx = d.x * aw + acx;
    float pcy = d.y * ah + acy;
    float pw = expf(dw) * aw;
    float ph = expf(dh) * ah;
    float x1 = fminf(fmaxf(pcx - 0.5f * pw, 0.0f), imw);
    float y1 = fminf(fmaxf(pcy - 0.5f * ph, 0.0f), imh);
    float x2 = fminf(fmaxf(pcx + 0.5f * pw, 0.0f), imw);
    float y2 = fminf(fmaxf(pcy + 0.5f * ph, 0.0f), imh);
    boxes[off] = make_float4(x1, y1, x2, y2);
    float area = (x2 - x1) * (y2 - y1);
    float sc = (area > 1.0f) ? obj[off] : -__builtin_inff();
    unsigned u = orderable(sc);
    keys[off] = u;
    atomicAdd(&hist[(size_t)b * NBINS + (u >> 16)], 1u);
  }
}

// One block per batch. Select top-score band via histogram, compact+sort in
// LDS, greedy-scan against kept list. Continuation loop handles (rare) chunk
// exhaustion so correctness never depends on suppression being rare.
__global__ void __launch_bounds__(BT) nms_kernel(const float4* __restrict__ boxes,
                                                 const unsigned* __restrict__ keys,
                                                 const unsigned* __restrict__ hist,
                                                 float* __restrict__ out,
                                                 int N, int K) {
#pragma clang fp contract(off)
  __shared__ unsigned long long s_key[CAP_SORT];  // 16 KB
  __shared__ float4 s_box[CAP_C];                 // 24 KB
  __shared__ float4 s_kept[KMAX];                 // ~16 KB (persists across chunks)
  __shared__ unsigned s_part[BT];                 // 1 KB scan scratch
  __shared__ unsigned s_misc[4];                  // 0: count, 1: T_lo, 2/3: sup flags
  const int b = blockIdx.x;
  const int t = threadIdx.x;
  const unsigned* h = hist + (size_t)b * NBINS;
  const unsigned* kb = keys + (size_t)b * N;
  const float4* bbx = boxes + (size_t)b * N;
  int nk = 0;
  unsigned T_hi = NBINS;
  if (t == 0) { s_misc[2] = 0u; s_misc[3] = 0u; }

  while (true) {
    // ---- Phase A: pick threshold bin T_lo so bins [T_lo, T_hi) hold ~TARGET cands
    if (t == 0) { s_misc[0] = 0u; s_misc[1] = 0xFFFFFFFFu; }
    const int BPT = NBINS / BT;  // bins per thread
    const int lo = t * BPT;
    unsigned mysum = 0;
    for (int k2 = 0; k2 < BPT; ++k2) {
      unsigned bin = (unsigned)(lo + k2);
      if (bin >= 128u && bin < T_hi) mysum += h[bin];  // bin>=128 <=> finite score
    }
    s_part[t] = mysum;
    __syncthreads();
    for (int d = 1; d < BT; d <<= 1) {  // inclusive suffix sum
      unsigned v = (t + d < BT) ? s_part[t + d] : 0u;
      __syncthreads();
      s_part[t] += v;
      __syncthreads();
    }
    unsigned total = s_part[0];
    if (total == 0u) break;
    unsigned target = (TARGET < total) ? TARGET : total;
    unsigned above = (t + 1 < BT) ? s_part[t + 1] : 0u;
    unsigned St = s_part[t];
    if (above < target && St >= target) {  // unique crossing thread
      unsigned c = above;
      for (int k2 = BPT - 1; k2 >= 0; --k2) {
        unsigned bin = (unsigned)(lo + k2);
        if (bin >= 128u && bin < T_hi) {
          unsigned hv = h[bin];
          c += hv;
          if (c >= target) {
            unsigned T = bin;
            if (c > CAP_C && (c - hv) > 0u) T = bin + 1u;  // avoid LDS overflow
            s_misc[1] = T;
            break;
          }
        }
      }
    }
    __syncthreads();
    unsigned T_lo = s_misc[1];
    if (T_lo == 0xFFFFFFFFu) break;

    // ---- Phase B: compact candidates with bin in [T_lo, T_hi) into LDS
    for (int i = t; i < CAP_SORT; i += BT) s_key[i] = 0ull;  // pad sinks to end
    __syncthreads();
    for (int i = t; i < N; i += BT) {
      unsigned u = kb[i];
      unsigned bin = u >> 16;
      if (bin >= T_lo && bin < T_hi) {
        unsigned p = atomicAdd(&s_misc[0], 1u);
        if (p < CAP_C)
          s_key[p] = ((unsigned long long)u << 32) | (unsigned)(~i);  // ~i: argmax low-idx tiebreak
      }
    }
    __syncthreads();
    int cnt = (int)s_misc[0];
    if (cnt > CAP_C) cnt = CAP_C;
    if (cnt == 0) {
      __syncthreads();  // protect s_misc/s_part reuse
      if (T_lo <= 128u || T_lo >= T_hi) break;
      T_hi = T_lo;
      continue;
    }

    // ---- Phase C: bitonic sort descending over CAP_SORT keys
    for (unsigned kk = 2; kk <= CAP_SORT; kk <<= 1) {
      for (unsigned j = kk >> 1; j >= 1u; j >>= 1) {
        for (unsigned pid = t; pid < CAP_SORT / 2; pid += BT) {
          unsigned i = ((pid & ~(j - 1u)) << 1) | (pid & (j - 1u));
          unsigned p = i | j;
          unsigned long long va = s_key[i], vb = s_key[p];
          bool up = ((i & kk) == 0u);
          bool sw = up ? (va < vb) : (va > vb);
          if (sw) { s_key[i] = vb; s_key[p] = va; }
        }
        __syncthreads();
      }
    }

    // ---- Phase D: gather candidate boxes in sorted order
    for (int i = t; i < cnt; i += BT) {
      unsigned idx = ~(unsigned)(s_key[i] & 0xFFFFFFFFull);
      s_box[i] = bbx[idx];
    }
    __syncthreads();

    // ---- Phase E: serial greedy scan, parallel kept-check
    for (int c = 0; c < cnt && nk < K; ++c) {
      float4 cb = s_box[c];
      int f = 2 + (c & 1);  // double-buffered suppress flag
      bool found = false;
      for (int q = t; q < nk; q += BT) {
        float4 kp = s_kept[q];
        float ix1 = fmaxf(kp.x, cb.x), iy1 = fmaxf(kp.y, cb.y);
        float ix2 = fminf(kp.z, cb.z), iy2 = fminf(kp.w, cb.w);
        float inter = fmaxf(ix2 - ix1, 0.0f) * fmaxf(iy2 - iy1, 0.0f);
        float ka = (kp.z - kp.x) * (kp.w - kp.y);
        float ca = (cb.z - cb.x) * (cb.w - cb.y);
        float iou = inter / (ka + ca - inter + 1e-9f);
        if (iou > 0.7f) { found = true; break; }
      }
      if (found) s_misc[f] = 1u;
      __syncthreads();  // A: flag visible
      unsigned sup = s_misc[f];
      if (!sup && t == 0) {
        s_kept[nk] = cb;
        unsigned u = (unsigned)(s_key[c] >> 32);
        unsigned sb = (u & 0x80000000u) ? (u ^ 0x80000000u) : ~u;  // invert orderable
        float sc = __uint_as_float(sb);
        float* row = out + ((size_t)b * K + nk) * 6;
        row[0] = cb.x; row[1] = cb.y; row[2] = cb.z; row[3] = cb.w;
        row[4] = sc; row[5] = 1.0f;
      }
      __syncthreads();  // B: kept write visible, all read flag
      if (t == 0) s_misc[f] = 0u;  // safe: next writer of this buffer is 2 barriers away
      if (!sup) nk++;
    }
    if (nk >= K) break;
    if (T_lo <= 128u) break;  // consumed everything finite
    T_hi = T_lo;
    __syncthreads();
  }
  // rows [nk, K) already zeroed by init_kernel (matches reference invalid-slot zeros)
}

extern "C" void kernel_launch(void* const* d_in, const int* in_sizes, int n_in,
                              void* d_out, int out_size, void* d_ws, size_t ws_size,
                              hipStream_t stream) {
  const float4* anchors = (const float4*)d_in[0];
  const float4* deltas = (const float4*)d_in[1];
  const float* obj = (const float*)d_in[2];
  const int* imh = (const int*)d_in[3];
  const int* imw = (const int*)d_in[4];
  int N = in_sizes[0] / 4;
  int B = in_sizes[2] / N;
  int K = out_size / (B * 6);
  if (K > KMAX) K = KMAX;

  char* ws = (char*)d_ws;
  float4* boxes = (float4*)ws;                                   // B*N*16 bytes
  unsigned* keys = (unsigned*)(ws + (size_t)B * N * 16);         // B*N*4 bytes
  unsigned* hist = (unsigned*)(ws + (size_t)B * N * 20);         // B*NBINS*4 bytes
  float* out = (float*)d_out;

  init_kernel<<<512, 256, 0, stream>>>(hist, B * NBINS, out, out_size);
  int blocks = (N + 255) / 256;
  decode_kernel<<<blocks, 256, 0, stream>>>(anchors, deltas, obj, imh, imw,
                                            boxes, keys, hist, N, B);
  nms_kernel<<<B, BT, 0, stream>>>(boxes, keys, hist, out, N, K);
}

// Round 2
// 770.776 us; speedup vs baseline: 1.7598x; 1.7598x over previous
//
#include <hip/hip_runtime.h>
#include <cstdint>
#include <cstddef>

#define NBINS 65536         // 16-bit histogram of orderable score
#define CAP_C 2048          // candidate pool (pow2, = sort size)
#define NW (CAP_C / 64)     // 64-bit mask words per row = 32
#define TARGET 1792u        // threshold target (headroom to CAP_C)
#define KMAX 1008           // kept-list capacity
#define PD 16               // walk prefetch depth
#define MROWS 16            // rows per mask block

__device__ __forceinline__ unsigned orderable(float f) {
  unsigned b = __float_as_uint(f);
  return (b & 0x80000000u) ? ~b : (b | 0x80000000u);
}

__global__ void init_kernel(unsigned* __restrict__ hist, int histN,
                            unsigned* __restrict__ tc, int tcN,
                            float* __restrict__ out, int outN) {
  int i = blockIdx.x * blockDim.x + threadIdx.x;
  int stride = gridDim.x * blockDim.x;
  for (int j = i; j < histN; j += stride) hist[j] = 0u;
  for (int j = i; j < tcN; j += stride) tc[j] = 0u;
  for (int j = i; j < outN; j += stride) out[j] = 0.0f;
}

__global__ void decode_kernel(const float4* __restrict__ anchors,
                              const float4* __restrict__ deltas,
                              const float* __restrict__ obj,
                              const int* __restrict__ im_h_p,
                              const int* __restrict__ im_w_p,
                              float4* __restrict__ boxes,
                              unsigned* __restrict__ keys,
                              unsigned* __restrict__ hist,
                              int N, int B) {
#pragma clang fp contract(off)
  int n = blockIdx.x * blockDim.x + threadIdx.x;
  if (n >= N) return;
  float imw = (float)(*im_w_p);
  float imh = (float)(*im_h_p);
  float4 a = anchors[n];
  float aw = a.z - a.x;
  float ah = a.w - a.y;
  float acx = a.x + 0.5f * aw;
  float acy = a.y + 0.5f * ah;
  const float LOGM = 4.135166556742356f;  // log(1000/16) rounded to f32
  for (int b = 0; b < B; ++b) {
    size_t off = (size_t)b * N + n;
    float4 d = deltas[off];
    float dw = fminf(d.z, LOGM), dh = fminf(d.w, LOGM);
    float pcx = d.x * aw + acx;
    float pcy = d.y * ah + acy;
    float pw = expf(dw) * aw;
    float ph = expf(dh) * ah;
    float x1 = fminf(fmaxf(pcx - 0.5f * pw, 0.0f), imw);
    float y1 = fminf(fmaxf(pcy - 0.5f * ph, 0.0f), imh);
    float x2 = fminf(fmaxf(pcx + 0.5f * pw, 0.0f), imw);
    float y2 = fminf(fmaxf(pcy + 0.5f * ph, 0.0f), imh);
    boxes[off] = make_float4(x1, y1, x2, y2);
    float area = (x2 - x1) * (y2 - y1);
    float sc = (area > 1.0f) ? obj[off] : -__builtin_inff();
    unsigned u = orderable(sc);
    keys[off] = u;
    atomicAdd(&hist[(size_t)b * NBINS + (u >> 16)], 1u);
  }
}

// One block per batch: pick bin threshold so [T_lo, NBINS) holds ~TARGET
// candidates (<= CAP_C). Same crossing logic as round 1 (exactness-preserving).
__global__ void __launch_bounds__(256) threshold_kernel(const unsigned* __restrict__ hist,
                                                        unsigned* __restrict__ T_lo) {
  const int BPT = NBINS / 256;  // 256 bins/thread, contiguous ownership
  __shared__ unsigned s_part[256];
  __shared__ unsigned s_T;
  int b = blockIdx.x, t = threadIdx.x;
  const unsigned* h = hist + (size_t)b * NBINS;
  if (t == 0) s_T = 0xFFFFFFFFu;
  unsigned mysum = 0;
  const uint4* h4 = (const uint4*)(h + t * BPT);
  for (int k = 0; k < BPT / 4; ++k) {
    int bin0 = t * BPT + k * 4;
    if (bin0 >= 128) {  // bin>=128 <=> finite score; 128 % 4 == 0
      uint4 v = h4[k];
      mysum += v.x + v.y + v.z + v.w;
    }
  }
  s_part[t] = mysum;
  __syncthreads();
  for (int d = 1; d < 256; d <<= 1) {  // inclusive suffix sum
    unsigned v = (t + d < 256) ? s_part[t + d] : 0u;
    __syncthreads();
    s_part[t] += v;
    __syncthreads();
  }
  unsigned total = s_part[0];
  unsigned target = (TARGET < total) ? TARGET : total;
  unsigned above = (t + 1 < 256) ? s_part[t + 1] : 0u;
  if (total > 0u && above < target && s_part[t] >= target) {  // unique crossing thread
    unsigned c = above;
    for (int k = BPT - 1; k >= 0; --k) {
      unsigned bin = (unsigned)(t * BPT + k);
      if (bin < 128u) break;
      unsigned hv = h[bin];
      c += hv;
      if (c >= target) {
        unsigned T = bin;
        if (c > CAP_C && (c - hv) > 0u) T = bin + 1u;  // never overflow CAP_C
        s_T = T;
        break;
      }
    }
  }
  __syncthreads();
  if (t == 0) T_lo[b] = (total == 0u) ? 0xFFFFFFFFu : s_T;
}

// Full-GPU grid: append candidates above threshold to per-batch list.
__global__ void compact_kernel(const unsigned* __restrict__ keys,
                               const unsigned* __restrict__ T_lo,
                               unsigned long long* __restrict__ cand,
                               unsigned* __restrict__ cnt, int N) {
  int b = blockIdx.y;
  int i = blockIdx.x * blockDim.x + threadIdx.x;
  if (i >= N) return;
  unsigned u = keys[(size_t)b * N + i];
  if ((u >> 16) >= T_lo[b]) {
    unsigned p = atomicAdd(&cnt[b], 1u);
    if (p < CAP_C)  // ~i: argmax lowest-index tie-break after descending sort
      cand[(size_t)b * CAP_C + p] = ((unsigned long long)u << 32) | (unsigned)(~i);
  }
}

// One block per batch: bitonic sort CAP_C keys descending, gather sorted boxes.
__global__ void __launch_bounds__(1024) sort_kernel(const unsigned long long* __restrict__ cand,
                                                    const unsigned* __restrict__ cntp,
                                                    const float4* __restrict__ boxes,
                                                    float4* __restrict__ sboxes,
                                                    float* __restrict__ sscore,
                                                    int N) {
  __shared__ unsigned long long sk[CAP_C];  // 16 KB
  int b = blockIdx.x, t = threadIdx.x;
  int cnt = (int)cntp[b];
  if (cnt > CAP_C) cnt = CAP_C;
  for (int i = t; i < CAP_C; i += 1024)
    sk[i] = (i < cnt) ? cand[(size_t)b * CAP_C + i] : 0ull;  // pad sinks to end
  __syncthreads();
  for (unsigned kk = 2; kk <= CAP_C; kk <<= 1) {
    for (unsigned j = kk >> 1; j >= 1u; j >>= 1) {
      unsigned pid = (unsigned)t;  // exactly CAP_C/2 pairs
      unsigned i = ((pid & ~(j - 1u)) << 1) | (pid & (j - 1u));
      unsigned p = i | j;
      unsigned long long va = sk[i], vb = sk[p];
      bool up = ((i & kk) == 0u);
      bool sw = up ? (va < vb) : (va > vb);
      if (sw) { sk[i] = vb; sk[p] = va; }
      __syncthreads();
    }
  }
  for (int i = t; i < CAP_C; i += 1024) {
    unsigned long long key = sk[i];
    float4 bx = make_float4(0.f, 0.f, 0.f, 0.f);
    float sc = -__builtin_inff();
    if (i < cnt) {
      unsigned idx = ~(unsigned)(key & 0xFFFFFFFFull);
      bx = boxes[(size_t)b * N + idx];
      unsigned u = (unsigned)(key >> 32);
      unsigned sb2 = (u & 0x80000000u) ? (u ^ 0x80000000u) : ~u;
      sc = __uint_as_float(sb2);
    }
    sboxes[(size_t)b * CAP_C + i] = bx;
    sscore[(size_t)b * CAP_C + i] = sc;
  }
}

// Pairwise suppression masks: bit l of word w in row i <=> IoU(i, 64w+l) > 0.7.
// Grid (CAP_C/MROWS, B) x 256. Identical IoU op order to round 1 -> bit-exact.
__global__ void __launch_bounds__(256) mask_kernel(const float4* __restrict__ sboxes,
                                                   unsigned long long* __restrict__ mask) {
#pragma clang fp contract(off)
  __shared__ float4 sb[CAP_C];  // 32 KB
  int b = blockIdx.y, t = threadIdx.x;
  int wave = t >> 6, lane = t & 63;
  const float4* src = sboxes + (size_t)b * CAP_C;
  for (int i = t; i < CAP_C; i += 256) sb[i] = src[i];
  __syncthreads();
  for (int r = 0; r < MROWS; ++r) {
    int row = blockIdx.x * MROWS + r;
    float4 rb = sb[row];                       // broadcast read
    float ra = (rb.z - rb.x) * (rb.w - rb.y);  // picked-box area (barea)
    for (int chunk = wave; chunk < NW; chunk += 4) {
      float4 cb = sb[chunk * 64 + lane];
      float ix1 = fmaxf(rb.x, cb.x), iy1 = fmaxf(rb.y, cb.y);
      float ix2 = fminf(rb.z, cb.z), iy2 = fminf(rb.w, cb.w);
      float inter = fmaxf(ix2 - ix1, 0.0f) * fmaxf(iy2 - iy1, 0.0f);
      float ca = (cb.z - cb.x) * (cb.w - cb.y);
      float iou = inter / (ra + ca - inter + 1e-9f);
      unsigned long long bal = __ballot(iou > 0.7f);
      if (lane == 0)
        mask[((size_t)b * CAP_C + row) * NW + chunk] = bal;
    }
  }
}

// One wave per batch: serial greedy walk over the bitmask. Chain per candidate:
// bit-test -> __any -> conditional OR. Mask rows prefetched PD-deep (decision-
// independent addresses) so global latency never enters the chain.
__global__ void __launch_bounds__(64) walk_kernel(const unsigned long long* __restrict__ mask,
                                                  const float4* __restrict__ sboxes,
                                                  const float* __restrict__ sscore,
                                                  const unsigned* __restrict__ cntp,
                                                  float* __restrict__ out, int K) {
  __shared__ int s_keep[KMAX];
  int b = blockIdx.x, lane = threadIdx.x;
  const unsigned long long* M = mask + (size_t)b * CAP_C * NW;
  int cnt = (int)cntp[b];
  if (cnt > CAP_C) cnt = CAP_C;
  bool ow = lane < NW;
  unsigned long long removed = 0ull;
  unsigned long long pf[PD];
#pragma unroll
  for (int k = 0; k < PD; ++k)
    pf[k] = (ow && k < cnt) ? M[(size_t)k * NW + lane] : 0ull;
  int nk = 0;
  for (int base = 0; base < cnt && nk < K; base += PD) {
#pragma unroll
    for (int k = 0; k < PD; ++k) {
      int i = base + k;
      if (i >= cnt || nk >= K) break;
      unsigned long long m = pf[k];
      int nx = i + PD;
      pf[k] = (ow && nx < cnt) ? M[(size_t)nx * NW + lane] : 0ull;
      bool mybit = (lane == (i >> 6)) && ((removed >> (i & 63)) & 1ull);
      if (!__any((int)mybit)) {   // not suppressed by any earlier keep
        removed |= m;
        if (lane == 0) s_keep[nk] = i;
        ++nk;
      }
    }
  }
  __syncthreads();
  for (int j = lane; j < nk; j += 64) {
    int i = s_keep[j];
    float4 bx = sboxes[(size_t)b * CAP_C + i];
    float sc = sscore[(size_t)b * CAP_C + i];
    float* row = out + ((size_t)b * K + j) * 6;
    row[0] = bx.x; row[1] = bx.y; row[2] = bx.z; row[3] = bx.w;
    row[4] = sc; row[5] = 1.0f;
  }
  // rows [nk, K) stay zero from init (reference pads invalid slots with zeros)
}

extern "C" void kernel_launch(void* const* d_in, const int* in_sizes, int n_in,
                              void* d_out, int out_size, void* d_ws, size_t ws_size,
                              hipStream_t stream) {
  const float4* anchors = (const float4*)d_in[0];
  const float4* deltas = (const float4*)d_in[1];
  const float* obj = (const float*)d_in[2];
  const int* imh = (const int*)d_in[3];
  const int* imw = (const int*)d_in[4];
  int N = in_sizes[0] / 4;
  int B = in_sizes[2] / N;
  int K = out_size / (B * 6);
  if (K > KMAX) K = KMAX;

  // ws layout (alignment-descending)
  char* ws = (char*)d_ws;
  size_t off = 0;
  float4* boxes = (float4*)(ws + off);            off += (size_t)B * N * 16;
  float4* sboxes = (float4*)(ws + off);           off += (size_t)B * CAP_C * 16;
  unsigned long long* cand = (unsigned long long*)(ws + off); off += (size_t)B * CAP_C * 8;
  unsigned long long* mask = (unsigned long long*)(ws + off); off += (size_t)B * CAP_C * NW * 8;
  unsigned* keys = (unsigned*)(ws + off);         off += (size_t)B * N * 4;
  unsigned* hist = (unsigned*)(ws + off);         off += (size_t)B * NBINS * 4;
  float* sscore = (float*)(ws + off);             off += (size_t)B * CAP_C * 4;
  unsigned* T_lo = (unsigned*)(ws + off);         off += (size_t)B * 4;
  unsigned* cnt = (unsigned*)(ws + off);          off += (size_t)B * 4;
  float* out = (float*)d_out;

  int nb = (N + 255) / 256;
  init_kernel<<<256, 256, 0, stream>>>(hist, B * NBINS, T_lo, 2 * B, out, out_size);
  decode_kernel<<<nb, 256, 0, stream>>>(anchors, deltas, obj, imh, imw,
                                        boxes, keys, hist, N, B);
  threshold_kernel<<<B, 256, 0, stream>>>(hist, T_lo);
  compact_kernel<<<dim3(nb, B), 256, 0, stream>>>(keys, T_lo, cand, cnt, N);
  sort_kernel<<<B, 1024, 0, stream>>>(cand, cnt, boxes, sboxes, sscore, N);
  mask_kernel<<<dim3(CAP_C / MROWS, B), 256, 0, stream>>>(sboxes, mask);
  walk_kernel<<<B, 64, 0, stream>>>(mask, sboxes, sscore, cnt, out, K);
}

// Round 3
// 497.397 us; speedup vs baseline: 2.7270x; 1.5496x over previous
//
#include <hip/hip_runtime.h>
#include <cstdint>
#include <cstddef>

#define NBINS 65536         // 16-bit histogram of orderable score
#define CAP_C 2048          // candidate pool (pow2, = sort size)
#define NW (CAP_C / 64)     // 64-bit mask words per row = 32
#define TARGET 1792u        // threshold target (headroom to CAP_C)
#define KMAX 1008           // kept-list capacity
#define PD 24               // walk prefetch depth (in-register, 48 VGPRs)
#define MROWS 16            // rows per mask block

__device__ __forceinline__ unsigned orderable(float f) {
  unsigned b = __float_as_uint(f);
  return (b & 0x80000000u) ? ~b : (b | 0x80000000u);
}

__global__ void init_kernel(unsigned* __restrict__ hist, int histN,
                            unsigned* __restrict__ tc, int tcN,
                            float* __restrict__ out, int outN) {
  int i = blockIdx.x * blockDim.x + threadIdx.x;
  int stride = gridDim.x * blockDim.x;
  for (int j = i; j < histN; j += stride) hist[j] = 0u;
  for (int j = i; j < tcN; j += stride) tc[j] = 0u;
  for (int j = i; j < outN; j += stride) out[j] = 0.0f;
}

__global__ void decode_kernel(const float4* __restrict__ anchors,
                              const float4* __restrict__ deltas,
                              const float* __restrict__ obj,
                              const int* __restrict__ im_h_p,
                              const int* __restrict__ im_w_p,
                              float4* __restrict__ boxes,
                              unsigned* __restrict__ keys,
                              unsigned* __restrict__ hist,
                              int N, int B) {
#pragma clang fp contract(off)
  int n = blockIdx.x * blockDim.x + threadIdx.x;
  if (n >= N) return;
  float imw = (float)(*im_w_p);
  float imh = (float)(*im_h_p);
  float4 a = anchors[n];
  float aw = a.z - a.x;
  float ah = a.w - a.y;
  float acx = a.x + 0.5f * aw;
  float acy = a.y + 0.5f * ah;
  const float LOGM = 4.135166556742356f;  // log(1000/16) rounded to f32
  for (int b = 0; b < B; ++b) {
    size_t off = (size_t)b * N + n;
    float4 d = deltas[off];
    float dw = fminf(d.z, LOGM), dh = fminf(d.w, LOGM);
    float pcx = d.x * aw + acx;
    float pcy = d.y * ah + acy;
    float pw = expf(dw) * aw;
    float ph = expf(dh) * ah;
    float x1 = fminf(fmaxf(pcx - 0.5f * pw, 0.0f), imw);
    float y1 = fminf(fmaxf(pcy - 0.5f * ph, 0.0f), imh);
    float x2 = fminf(fmaxf(pcx + 0.5f * pw, 0.0f), imw);
    float y2 = fminf(fmaxf(pcy + 0.5f * ph, 0.0f), imh);
    boxes[off] = make_float4(x1, y1, x2, y2);
    float area = (x2 - x1) * (y2 - y1);
    float sc = (area > 1.0f) ? obj[off] : -__builtin_inff();
    unsigned u = orderable(sc);
    keys[off] = u;
    atomicAdd(&hist[(size_t)b * NBINS + (u >> 16)], 1u);
  }
}

// One block per batch: pick bin threshold so [T_lo, NBINS) holds ~TARGET
// candidates (<= CAP_C).
__global__ void __launch_bounds__(256) threshold_kernel(const unsigned* __restrict__ hist,
                                                        unsigned* __restrict__ T_lo) {
  const int BPT = NBINS / 256;  // 256 bins/thread, contiguous ownership
  __shared__ unsigned s_part[256];
  __shared__ unsigned s_T;
  int b = blockIdx.x, t = threadIdx.x;
  const unsigned* h = hist + (size_t)b * NBINS;
  if (t == 0) s_T = 0xFFFFFFFFu;
  unsigned mysum = 0;
  const uint4* h4 = (const uint4*)(h + t * BPT);
  for (int k = 0; k < BPT / 4; ++k) {
    int bin0 = t * BPT + k * 4;
    if (bin0 >= 128) {  // bin>=128 <=> finite score; 128 % 4 == 0
      uint4 v = h4[k];
      mysum += v.x + v.y + v.z + v.w;
    }
  }
  s_part[t] = mysum;
  __syncthreads();
  for (int d = 1; d < 256; d <<= 1) {  // inclusive suffix sum
    unsigned v = (t + d < 256) ? s_part[t + d] : 0u;
    __syncthreads();
    s_part[t] += v;
    __syncthreads();
  }
  unsigned total = s_part[0];
  unsigned target = (TARGET < total) ? TARGET : total;
  unsigned above = (t + 1 < 256) ? s_part[t + 1] : 0u;
  if (total > 0u && above < target && s_part[t] >= target) {  // unique crossing thread
    unsigned c = above;
    for (int k = BPT - 1; k >= 0; --k) {
      unsigned bin = (unsigned)(t * BPT + k);
      if (bin < 128u) break;
      unsigned hv = h[bin];
      c += hv;
      if (c >= target) {
        unsigned T = bin;
        if (c > CAP_C && (c - hv) > 0u) T = bin + 1u;  // never overflow CAP_C
        s_T = T;
        break;
      }
    }
  }
  __syncthreads();
  if (t == 0) T_lo[b] = (total == 0u) ? 0xFFFFFFFFu : s_T;
}

// Full-GPU grid: append candidates above threshold to per-batch list.
__global__ void compact_kernel(const unsigned* __restrict__ keys,
                               const unsigned* __restrict__ T_lo,
                               unsigned long long* __restrict__ cand,
                               unsigned* __restrict__ cnt, int N) {
  int b = blockIdx.y;
  int i = blockIdx.x * blockDim.x + threadIdx.x;
  if (i >= N) return;
  unsigned u = keys[(size_t)b * N + i];
  if ((u >> 16) >= T_lo[b]) {
    unsigned p = atomicAdd(&cnt[b], 1u);
    if (p < CAP_C)  // ~i: argmax lowest-index tie-break after descending sort
      cand[(size_t)b * CAP_C + p] = ((unsigned long long)u << 32) | (unsigned)(~i);
  }
}

// One block per batch: bitonic sort CAP_C keys descending, gather sorted boxes.
__global__ void __launch_bounds__(1024) sort_kernel(const unsigned long long* __restrict__ cand,
                                                    const unsigned* __restrict__ cntp,
                                                    const float4* __restrict__ boxes,
                                                    float4* __restrict__ sboxes,
                                                    float* __restrict__ sscore,
                                                    int N) {
  __shared__ unsigned long long sk[CAP_C];  // 16 KB
  int b = blockIdx.x, t = threadIdx.x;
  int cnt = (int)cntp[b];
  if (cnt > CAP_C) cnt = CAP_C;
  for (int i = t; i < CAP_C; i += 1024)
    sk[i] = (i < cnt) ? cand[(size_t)b * CAP_C + i] : 0ull;  // pad sinks to end
  __syncthreads();
  for (unsigned kk = 2; kk <= CAP_C; kk <<= 1) {
    for (unsigned j = kk >> 1; j >= 1u; j >>= 1) {
      unsigned pid = (unsigned)t;  // exactly CAP_C/2 pairs
      unsigned i = ((pid & ~(j - 1u)) << 1) | (pid & (j - 1u));
      unsigned p = i | j;
      unsigned long long va = sk[i], vb = sk[p];
      bool up = ((i & kk) == 0u);
      bool sw = up ? (va < vb) : (va > vb);
      if (sw) { sk[i] = vb; sk[p] = va; }
      __syncthreads();
    }
  }
  for (int i = t; i < CAP_C; i += 1024) {
    unsigned long long key = sk[i];
    float4 bx = make_float4(0.f, 0.f, 0.f, 0.f);
    float sc = -__builtin_inff();
    if (i < cnt) {
      unsigned idx = ~(unsigned)(key & 0xFFFFFFFFull);
      bx = boxes[(size_t)b * N + idx];
      unsigned u = (unsigned)(key >> 32);
      unsigned sb2 = (u & 0x80000000u) ? (u ^ 0x80000000u) : ~u;
      sc = __uint_as_float(sb2);
    }
    sboxes[(size_t)b * CAP_C + i] = bx;
    sscore[(size_t)b * CAP_C + i] = sc;
  }
}

// Pairwise suppression masks: bit l of word w in row i <=> IoU(i, 64w+l) > 0.7.
__global__ void __launch_bounds__(256) mask_kernel(const float4* __restrict__ sboxes,
                                                   unsigned long long* __restrict__ mask) {
#pragma clang fp contract(off)
  __shared__ float4 sb[CAP_C];  // 32 KB
  int b = blockIdx.y, t = threadIdx.x;
  int wave = t >> 6, lane = t & 63;
  const float4* src = sboxes + (size_t)b * CAP_C;
  for (int i = t; i < CAP_C; i += 256) sb[i] = src[i];
  __syncthreads();
  for (int r = 0; r < MROWS; ++r) {
    int row = blockIdx.x * MROWS + r;
    float4 rb = sb[row];                       // broadcast read
    float ra = (rb.z - rb.x) * (rb.w - rb.y);  // picked-box area (barea)
    for (int chunk = wave; chunk < NW; chunk += 4) {
      float4 cb = sb[chunk * 64 + lane];
      float ix1 = fmaxf(rb.x, cb.x), iy1 = fmaxf(rb.y, cb.y);
      float ix2 = fminf(rb.z, cb.z), iy2 = fminf(rb.w, cb.w);
      float inter = fmaxf(ix2 - ix1, 0.0f) * fmaxf(iy2 - iy1, 0.0f);
      float ca = (cb.z - cb.x) * (cb.w - cb.y);
      float iou = inter / (ra + ca - inter + 1e-9f);
      unsigned long long bal = __ballot(iou > 0.7f);
      if (lane == 0)
        mask[((size_t)b * CAP_C + row) * NW + chunk] = bal;
    }
  }
}

// One wave per batch: serial greedy walk over the bitmask.
// PD-deep register pipeline: fixed-trip unrolled inner loop, NO break inside
// the unrolled body (round-2's break demoted pf[] to scratch -> vmcnt(0) +
// scratch latency in the serial chain, 970 cyc/iter). Loads are unconditional
// with clamped row index (mask has all CAP_C rows written), decisions are
// predicated -> bitwise-identical keep sequence.
__global__ void __launch_bounds__(64) walk_kernel(const unsigned long long* __restrict__ mask,
                                                  const float4* __restrict__ sboxes,
                                                  const float* __restrict__ sscore,
                                                  const unsigned* __restrict__ cntp,
                                                  float* __restrict__ out, int K) {
  __shared__ int s_keep[KMAX];
  int b = blockIdx.x, lane = threadIdx.x;
  const unsigned long long* M = mask + (size_t)b * CAP_C * NW;
  int cnt = (int)cntp[b];
  if (cnt > CAP_C) cnt = CAP_C;
  const bool ow = lane < NW;
  const unsigned long long* Ml = M + lane;  // lane's word column
  unsigned long long removed = 0ull;
  unsigned long long pf[PD];
#pragma unroll
  for (int k = 0; k < PD; ++k) {
    int r = (k < CAP_C) ? k : (CAP_C - 1);
    pf[k] = ow ? Ml[(size_t)r * NW] : 0ull;
  }
  int nk = 0;
  for (int base = 0; base < CAP_C; base += PD) {
    if (base >= cnt || nk >= K) break;  // chunk-granular exit (wave-uniform)
#pragma unroll
    for (int k = 0; k < PD; ++k) {
      int i = base + k;
      unsigned long long m = pf[k];
      int nx = i + PD;
      int r = (nx < CAP_C) ? nx : (CAP_C - 1);
      pf[k] = ow ? Ml[(size_t)r * NW] : 0ull;  // unconditional refill
      bool act = (i < cnt) && (nk < K);
      bool mybit = (lane == (i >> 6)) && ((removed >> (i & 63)) & 1ull);
      bool sup = __any((int)mybit);
      if (act && !sup) {
        removed |= m;
        if (lane == 0) s_keep[nk] = i;
        ++nk;
      }
    }
  }
  __syncthreads();
  for (int j = lane; j < nk; j += 64) {
    int i = s_keep[j];
    float4 bx = sboxes[(size_t)b * CAP_C + i];
    float sc = sscore[(size_t)b * CAP_C + i];
    float* row = out + ((size_t)b * K + j) * 6;
    row[0] = bx.x; row[1] = bx.y; row[2] = bx.z; row[3] = bx.w;
    row[4] = sc; row[5] = 1.0f;
  }
  // rows [nk, K) stay zero from init (reference pads invalid slots with zeros)
}

extern "C" void kernel_launch(void* const* d_in, const int* in_sizes, int n_in,
                              void* d_out, int out_size, void* d_ws, size_t ws_size,
                              hipStream_t stream) {
  const float4* anchors = (const float4*)d_in[0];
  const float4* deltas = (const float4*)d_in[1];
  const float* obj = (const float*)d_in[2];
  const int* imh = (const int*)d_in[3];
  const int* imw = (const int*)d_in[4];
  int N = in_sizes[0] / 4;
  int B = in_sizes[2] / N;
  int K = out_size / (B * 6);
  if (K > KMAX) K = KMAX;

  // ws layout (alignment-descending)
  char* ws = (char*)d_ws;
  size_t off = 0;
  float4* boxes = (float4*)(ws + off);            off += (size_t)B * N * 16;
  float4* sboxes = (float4*)(ws + off);           off += (size_t)B * CAP_C * 16;
  unsigned long long* cand = (unsigned long long*)(ws + off); off += (size_t)B * CAP_C * 8;
  unsigned long long* mask = (unsigned long long*)(ws + off); off += (size_t)B * CAP_C * NW * 8;
  unsigned* keys = (unsigned*)(ws + off);         off += (size_t)B * N * 4;
  unsigned* hist = (unsigned*)(ws + off);         off += (size_t)B * NBINS * 4;
  float* sscore = (float*)(ws + off);             off += (size_t)B * CAP_C * 4;
  unsigned* T_lo = (unsigned*)(ws + off);         off += (size_t)B * 4;
  unsigned* cnt = (unsigned*)(ws + off);          off += (size_t)B * 4;
  float* out = (float*)d_out;

  int nb = (N + 255) / 256;
  init_kernel<<<256, 256, 0, stream>>>(hist, B * NBINS, T_lo, 2 * B, out, out_size);
  decode_kernel<<<nb, 256, 0, stream>>>(anchors, deltas, obj, imh, imw,
                                        boxes, keys, hist, N, B);
  threshold_kernel<<<B, 256, 0, stream>>>(hist, T_lo);
  compact_kernel<<<dim3(nb, B), 256, 0, stream>>>(keys, T_lo, cand, cnt, N);
  sort_kernel<<<B, 1024, 0, stream>>>(cand, cnt, boxes, sboxes, sscore, N);
  mask_kernel<<<dim3(CAP_C / MROWS, B), 256, 0, stream>>>(sboxes, mask);
  walk_kernel<<<B, 64, 0, stream>>>(mask, sboxes, sscore, cnt, out, K);
}

// Round 4
// 375.315 us; speedup vs baseline: 3.6140x; 1.3253x over previous
//
#include <hip/hip_runtime.h>
#include <cstdint>
#include <cstddef>

#define NBINS 65536         // 16-bit histogram of orderable score
#define CAP_C 2048          // candidate pool (pow2, = sort size)
#define NW (CAP_C / 64)     // 64-bit mask words per row = 32
#define TARGET 1792u        // threshold target (headroom to CAP_C)
#define KMAX 1008           // kept-list capacity
#define PD 24               // walk prefetch depth (in-register, 48 VGPRs)
#define MROWS 16            // rows per mask block
#define HB 1024             // hist block threads
#define HE 32768            // keys per hist block (16-bit pack: counts <= HE < 65536)

__device__ __forceinline__ unsigned orderable(float f) {
  unsigned b = __float_as_uint(f);
  return (b & 0x80000000u) ? ~b : (b | 0x80000000u);
}

// Pure streaming now: the global-atomic histogram (round-3: 1M contended
// atomics, ~140us of L2-line serialization) moved to hist_kernel. This kernel
// also zero-fills hist (removes init_kernel dispatch).
__global__ void decode_kernel(const float4* __restrict__ anchors,
                              const float4* __restrict__ deltas,
                              const float* __restrict__ obj,
                              const int* __restrict__ im_h_p,
                              const int* __restrict__ im_w_p,
                              float4* __restrict__ boxes,
                              unsigned* __restrict__ keys,
                              unsigned* __restrict__ hist,
                              int N, int B) {
#pragma clang fp contract(off)
  int n = blockIdx.x * blockDim.x + threadIdx.x;
  int stride = gridDim.x * blockDim.x;
  for (int j = n; j < B * NBINS; j += stride) hist[j] = 0u;
  if (n >= N) return;
  float imw = (float)(*im_w_p);
  float imh = (float)(*im_h_p);
  float4 a = anchors[n];
  float aw = a.z - a.x;
  float ah = a.w - a.y;
  float acx = a.x + 0.5f * aw;
  float acy = a.y + 0.5f * ah;
  const float LOGM = 4.135166556742356f;  // log(1000/16) rounded to f32
  for (int b = 0; b < B; ++b) {
    size_t off = (size_t)b * N + n;
    float4 d = deltas[off];
    float dw = fminf(d.z, LOGM), dh = fminf(d.w, LOGM);
    float pcx = d.x * aw + acx;
    float pcy = d.y * ah + acy;
    float pw = expf(dw) * aw;
    float ph = expf(dh) * ah;
    float x1 = fminf(fmaxf(pcx - 0.5f * pw, 0.0f), imw);
    float y1 = fminf(fmaxf(pcy - 0.5f * ph, 0.0f), imh);
    float x2 = fminf(fmaxf(pcx + 0.5f * pw, 0.0f), imw);
    float y2 = fminf(fmaxf(pcy + 0.5f * ph, 0.0f), imh);
    boxes[off] = make_float4(x1, y1, x2, y2);
    float area = (x2 - x1) * (y2 - y1);
    float sc = (area > 1.0f) ? obj[off] : -__builtin_inff();
    keys[off] = orderable(sc);
  }
}

// LDS-privatized histogram. Grid (P, 2, B): block (c, half, b) scans keys
// [c*HE, c*HE+HE) of batch b and histograms bins in [half*32768, +32768)
// into a 64KB LDS array (two 16-bit counts per uint; max count HE < 2^16).
// Flush: only nonzero bins hit global atomics -> <=P colliders per bin.
__global__ void __launch_bounds__(HB) hist_kernel(const unsigned* __restrict__ keys,
                                                  unsigned* __restrict__ hist,
                                                  int N) {
  __shared__ unsigned hl[NBINS / 4];  // 16384 uints = 64 KB
  int t = threadIdx.x;
  int half = blockIdx.y, b = blockIdx.z;
  unsigned lo_bin = (unsigned)half * 32768u;
  for (int i = t; i < NBINS / 4; i += HB) hl[i] = 0u;
  __syncthreads();
  const unsigned* kb = keys + (size_t)b * N;
  int base = blockIdx.x * HE;
  int end = base + HE;
  if (end > N) end = N;
  for (int i = base + t; i < end; i += HB) {
    unsigned bin = kb[i] >> 16;
    unsigned lb = bin - lo_bin;
    if (lb < 32768u)
      atomicAdd(&hl[lb >> 1], (lb & 1u) ? 65536u : 1u);
  }
  __syncthreads();
  unsigned* hg = hist + (size_t)b * NBINS + lo_bin;
  for (int i = t; i < NBINS / 4; i += HB) {
    unsigned v = hl[i];
    unsigned clo = v & 0xFFFFu, chi = v >> 16;
    if (clo) atomicAdd(&hg[2 * i], clo);
    if (chi) atomicAdd(&hg[2 * i + 1], chi);
  }
}

// One block per batch: pick bin threshold so [T_lo, NBINS) holds ~TARGET
// candidates (<= CAP_C). Also zeroes cnt[b] for compact (init_kernel removed).
__global__ void __launch_bounds__(256) threshold_kernel(const unsigned* __restrict__ hist,
                                                        unsigned* __restrict__ T_lo,
                                                        unsigned* __restrict__ cnt) {
  const int BPT = NBINS / 256;  // 256 bins/thread, contiguous ownership
  __shared__ unsigned s_part[256];
  __shared__ unsigned s_T;
  int b = blockIdx.x, t = threadIdx.x;
  const unsigned* h = hist + (size_t)b * NBINS;
  if (t == 0) { s_T = 0xFFFFFFFFu; cnt[b] = 0u; }
  unsigned mysum = 0;
  const uint4* h4 = (const uint4*)(h + t * BPT);
  for (int k = 0; k < BPT / 4; ++k) {
    int bin0 = t * BPT + k * 4;
    if (bin0 >= 128) {  // bin>=128 <=> finite score; 128 % 4 == 0
      uint4 v = h4[k];
      mysum += v.x + v.y + v.z + v.w;
    }
  }
  s_part[t] = mysum;
  __syncthreads();
  for (int d = 1; d < 256; d <<= 1) {  // inclusive suffix sum
    unsigned v = (t + d < 256) ? s_part[t + d] : 0u;
    __syncthreads();
    s_part[t] += v;
    __syncthreads();
  }
  unsigned total = s_part[0];
  unsigned target = (TARGET < total) ? TARGET : total;
  unsigned above = (t + 1 < 256) ? s_part[t + 1] : 0u;
  if (total > 0u && above < target && s_part[t] >= target) {  // unique crossing thread
    unsigned c = above;
    for (int k = BPT - 1; k >= 0; --k) {
      unsigned bin = (unsigned)(t * BPT + k);
      if (bin < 128u) break;
      unsigned hv = h[bin];
      c += hv;
      if (c >= target) {
        unsigned T = bin;
        if (c > CAP_C && (c - hv) > 0u) T = bin + 1u;  // never overflow CAP_C
        s_T = T;
        break;
      }
    }
  }
  __syncthreads();
  if (t == 0) T_lo[b] = (total == 0u) ? 0xFFFFFFFFu : s_T;
}

// Full-GPU grid: append candidates above threshold to per-batch list.
__global__ void compact_kernel(const unsigned* __restrict__ keys,
                               const unsigned* __restrict__ T_lo,
                               unsigned long long* __restrict__ cand,
                               unsigned* __restrict__ cnt, int N) {
  int b = blockIdx.y;
  int i = blockIdx.x * blockDim.x + threadIdx.x;
  if (i >= N) return;
  unsigned u = keys[(size_t)b * N + i];
  if ((u >> 16) >= T_lo[b]) {
    unsigned p = atomicAdd(&cnt[b], 1u);
    if (p < CAP_C)  // ~i: argmax lowest-index tie-break after descending sort
      cand[(size_t)b * CAP_C + p] = ((unsigned long long)u << 32) | (unsigned)(~i);
  }
}

// One block per batch: bitonic sort CAP_C keys descending, gather sorted boxes.
__global__ void __launch_bounds__(1024) sort_kernel(const unsigned long long* __restrict__ cand,
                                                    const unsigned* __restrict__ cntp,
                                                    const float4* __restrict__ boxes,
                                                    float4* __restrict__ sboxes,
                                                    float* __restrict__ sscore,
                                                    int N) {
  __shared__ unsigned long long sk[CAP_C];  // 16 KB
  int b = blockIdx.x, t = threadIdx.x;
  int cnt = (int)cntp[b];
  if (cnt > CAP_C) cnt = CAP_C;
  for (int i = t; i < CAP_C; i += 1024)
    sk[i] = (i < cnt) ? cand[(size_t)b * CAP_C + i] : 0ull;  // pad sinks to end
  __syncthreads();
  for (unsigned kk = 2; kk <= CAP_C; kk <<= 1) {
    for (unsigned j = kk >> 1; j >= 1u; j >>= 1) {
      unsigned pid = (unsigned)t;  // exactly CAP_C/2 pairs
      unsigned i = ((pid & ~(j - 1u)) << 1) | (pid & (j - 1u));
      unsigned p = i | j;
      unsigned long long va = sk[i], vb = sk[p];
      bool up = ((i & kk) == 0u);
      bool sw = up ? (va < vb) : (va > vb);
      if (sw) { sk[i] = vb; sk[p] = va; }
      __syncthreads();
    }
  }
  for (int i = t; i < CAP_C; i += 1024) {
    unsigned long long key = sk[i];
    float4 bx = make_float4(0.f, 0.f, 0.f, 0.f);
    float sc = -__builtin_inff();
    if (i < cnt) {
      unsigned idx = ~(unsigned)(key & 0xFFFFFFFFull);
      bx = boxes[(size_t)b * N + idx];
      unsigned u = (unsigned)(key >> 32);
      unsigned sb2 = (u & 0x80000000u) ? (u ^ 0x80000000u) : ~u;
      sc = __uint_as_float(sb2);
    }
    sboxes[(size_t)b * CAP_C + i] = bx;
    sscore[(size_t)b * CAP_C + i] = sc;
  }
}

// Pairwise suppression masks: bit l of word w in row i <=> IoU(i, 64w+l) > 0.7.
__global__ void __launch_bounds__(256) mask_kernel(const float4* __restrict__ sboxes,
                                                   unsigned long long* __restrict__ mask) {
#pragma clang fp contract(off)
  __shared__ float4 sb[CAP_C];  // 32 KB
  int b = blockIdx.y, t = threadIdx.x;
  int wave = t >> 6, lane = t & 63;
  const float4* src = sboxes + (size_t)b * CAP_C;
  for (int i = t; i < CAP_C; i += 256) sb[i] = src[i];
  __syncthreads();
  for (int r = 0; r < MROWS; ++r) {
    int row = blockIdx.x * MROWS + r;
    float4 rb = sb[row];                       // broadcast read
    float ra = (rb.z - rb.x) * (rb.w - rb.y);  // picked-box area (barea)
    for (int chunk = wave; chunk < NW; chunk += 4) {
      float4 cb = sb[chunk * 64 + lane];
      float ix1 = fmaxf(rb.x, cb.x), iy1 = fmaxf(rb.y, cb.y);
      float ix2 = fminf(rb.z, cb.z), iy2 = fminf(rb.w, cb.w);
      float inter = fmaxf(ix2 - ix1, 0.0f) * fmaxf(iy2 - iy1, 0.0f);
      float ca = (cb.z - cb.x) * (cb.w - cb.y);
      float iou = inter / (ra + ca - inter + 1e-9f);
      unsigned long long bal = __ballot(iou > 0.7f);
      if (lane == 0)
        mask[((size_t)b * CAP_C + row) * NW + chunk] = bal;
    }
  }
}

// One wave per batch: serial greedy walk over the bitmask. PD-deep register
// pipeline, fixed-trip unrolled body (no break inside -> pf stays in VGPRs).
// Also zeroes output tail rows [nk, K) (init_kernel removed; out is poisoned).
__global__ void __launch_bounds__(64) walk_kernel(const unsigned long long* __restrict__ mask,
                                                  const float4* __restrict__ sboxes,
                                                  const float* __restrict__ sscore,
                                                  const unsigned* __restrict__ cntp,
                                                  float* __restrict__ out, int K) {
  __shared__ int s_keep[KMAX];
  int b = blockIdx.x, lane = threadIdx.x;
  const unsigned long long* M = mask + (size_t)b * CAP_C * NW;
  int cnt = (int)cntp[b];
  if (cnt > CAP_C) cnt = CAP_C;
  const bool ow = lane < NW;
  const unsigned long long* Ml = M + lane;  // lane's word column
  unsigned long long removed = 0ull;
  unsigned long long pf[PD];
#pragma unroll
  for (int k = 0; k < PD; ++k) {
    int r = (k < CAP_C) ? k : (CAP_C - 1);
    pf[k] = ow ? Ml[(size_t)r * NW] : 0ull;
  }
  int nk = 0;
  for (int base = 0; base < CAP_C; base += PD) {
    if (base >= cnt || nk >= K) break;  // chunk-granular exit (wave-uniform)
#pragma unroll
    for (int k = 0; k < PD; ++k) {
      int i = base + k;
      unsigned long long m = pf[k];
      int nx = i + PD;
      int r = (nx < CAP_C) ? nx : (CAP_C - 1);
      pf[k] = ow ? Ml[(size_t)r * NW] : 0ull;  // unconditional refill
      bool act = (i < cnt) && (nk < K);
      bool mybit = (lane == (i >> 6)) && ((removed >> (i & 63)) & 1ull);
      bool sup = __any((int)mybit);
      if (act && !sup) {
        removed |= m;
        if (lane == 0) s_keep[nk] = i;
        ++nk;
      }
    }
  }
  __syncthreads();
  for (int j = lane; j < nk; j += 64) {
    int i = s_keep[j];
    float4 bx = sboxes[(size_t)b * CAP_C + i];
    float sc = sscore[(size_t)b * CAP_C + i];
    float* row = out + ((size_t)b * K + j) * 6;
    row[0] = bx.x; row[1] = bx.y; row[2] = bx.z; row[3] = bx.w;
    row[4] = sc; row[5] = 1.0f;
  }
  for (int j = nk + lane; j < K; j += 64) {  // zero invalid tail rows
    float* row = out + ((size_t)b * K + j) * 6;
    row[0] = 0.f; row[1] = 0.f; row[2] = 0.f; row[3] = 0.f;
    row[4] = 0.f; row[5] = 0.f;
  }
}

extern "C" void kernel_launch(void* const* d_in, const int* in_sizes, int n_in,
                              void* d_out, int out_size, void* d_ws, size_t ws_size,
                              hipStream_t stream) {
  const float4* anchors = (const float4*)d_in[0];
  const float4* deltas = (const float4*)d_in[1];
  const float* obj = (const float*)d_in[2];
  const int* imh = (const int*)d_in[3];
  const int* imw = (const int*)d_in[4];
  int N = in_sizes[0] / 4;
  int B = in_sizes[2] / N;
  int K = out_size / (B * 6);
  if (K > KMAX) K = KMAX;

  // ws layout (alignment-descending)
  char* ws = (char*)d_ws;
  size_t off = 0;
  float4* boxes = (float4*)(ws + off);            off += (size_t)B * N * 16;
  float4* sboxes = (float4*)(ws + off);           off += (size_t)B * CAP_C * 16;
  unsigned long long* cand = (unsigned long long*)(ws + off); off += (size_t)B * CAP_C * 8;
  unsigned long long* mask = (unsigned long long*)(ws + off); off += (size_t)B * CAP_C * NW * 8;
  unsigned* keys = (unsigned*)(ws + off);         off += (size_t)B * N * 4;
  unsigned* hist = (unsigned*)(ws + off);         off += (size_t)B * NBINS * 4;
  float* sscore = (float*)(ws + off);             off += (size_t)B * CAP_C * 4;
  unsigned* T_lo = (unsigned*)(ws + off);         off += (size_t)B * 4;
  unsigned* cnt = (unsigned*)(ws + off);          off += (size_t)B * 4;
  float* out = (float*)d_out;

  int nb = (N + 255) / 256;
  int P = (N + HE - 1) / HE;
  decode_kernel<<<nb, 256, 0, stream>>>(anchors, deltas, obj, imh, imw,
                                        boxes, keys, hist, N, B);
  hist_kernel<<<dim3(P, 2, B), HB, 0, stream>>>(keys, hist, N);
  threshold_kernel<<<B, 256, 0, stream>>>(hist, T_lo, cnt);
  compact_kernel<<<dim3(nb, B), 256, 0, stream>>>(keys, T_lo, cand, cnt, N);
  sort_kernel<<<B, 1024, 0, stream>>>(cand, cnt, boxes, sboxes, sscore, N);
  mask_kernel<<<dim3(CAP_C / MROWS, B), 256, 0, stream>>>(sboxes, mask);
  walk_kernel<<<B, 64, 0, stream>>>(mask, sboxes, sscore, cnt, out, K);
}

// Round 5
// 358.886 us; speedup vs baseline: 3.7794x; 1.0458x over previous
//
#include <hip/hip_runtime.h>
#include <cstdint>
#include <cstddef>

#define NBINS 65536         // 16-bit histogram of orderable score
#define CAP_C 2048          // candidate pool (pow2, = sort size)
#define NW (CAP_C / 64)     // 64-bit mask words per row = 32
#define TARGET 1792u        // threshold target (headroom to CAP_C)
#define KMAX 1008           // kept-list capacity
#define MROWS 16            // rows per mask block
#define HB 1024             // hist block threads
#define HE 32768            // keys per hist block (16-bit pack: counts <= HE < 65536)

typedef unsigned long long u64;

__device__ __forceinline__ unsigned orderable(float f) {
  unsigned b = __float_as_uint(f);
  return (b & 0x80000000u) ? ~b : (b | 0x80000000u);
}

// Pure streaming: also zero-fills hist (no separate init dispatch).
__global__ void decode_kernel(const float4* __restrict__ anchors,
                              const float4* __restrict__ deltas,
                              const float* __restrict__ obj,
                              const int* __restrict__ im_h_p,
                              const int* __restrict__ im_w_p,
                              float4* __restrict__ boxes,
                              unsigned* __restrict__ keys,
                              unsigned* __restrict__ hist,
                              int N, int B) {
#pragma clang fp contract(off)
  int n = blockIdx.x * blockDim.x + threadIdx.x;
  int stride = gridDim.x * blockDim.x;
  for (int j = n; j < B * NBINS; j += stride) hist[j] = 0u;
  if (n >= N) return;
  float imw = (float)(*im_w_p);
  float imh = (float)(*im_h_p);
  float4 a = anchors[n];
  float aw = a.z - a.x;
  float ah = a.w - a.y;
  float acx = a.x + 0.5f * aw;
  float acy = a.y + 0.5f * ah;
  const float LOGM = 4.135166556742356f;  // log(1000/16) rounded to f32
  for (int b = 0; b < B; ++b) {
    size_t off = (size_t)b * N + n;
    float4 d = deltas[off];
    float dw = fminf(d.z, LOGM), dh = fminf(d.w, LOGM);
    float pcx = d.x * aw + acx;
    float pcy = d.y * ah + acy;
    float pw = expf(dw) * aw;
    float ph = expf(dh) * ah;
    float x1 = fminf(fmaxf(pcx - 0.5f * pw, 0.0f), imw);
    float y1 = fminf(fmaxf(pcy - 0.5f * ph, 0.0f), imh);
    float x2 = fminf(fmaxf(pcx + 0.5f * pw, 0.0f), imw);
    float y2 = fminf(fmaxf(pcy + 0.5f * ph, 0.0f), imh);
    boxes[off] = make_float4(x1, y1, x2, y2);
    float area = (x2 - x1) * (y2 - y1);
    float sc = (area > 1.0f) ? obj[off] : -__builtin_inff();
    keys[off] = orderable(sc);
  }
}

// LDS-privatized histogram (round-4 win: killed 140us of contended atomics).
__global__ void __launch_bounds__(HB) hist_kernel(const unsigned* __restrict__ keys,
                                                  unsigned* __restrict__ hist,
                                                  int N) {
  __shared__ unsigned hl[NBINS / 4];  // 16384 uints = 64 KB
  int t = threadIdx.x;
  int half = blockIdx.y, b = blockIdx.z;
  unsigned lo_bin = (unsigned)half * 32768u;
  for (int i = t; i < NBINS / 4; i += HB) hl[i] = 0u;
  __syncthreads();
  const unsigned* kb = keys + (size_t)b * N;
  int base = blockIdx.x * HE;
  int end = base + HE;
  if (end > N) end = N;
  for (int i = base + t; i < end; i += HB) {
    unsigned bin = kb[i] >> 16;
    unsigned lb = bin - lo_bin;
    if (lb < 32768u)
      atomicAdd(&hl[lb >> 1], (lb & 1u) ? 65536u : 1u);
  }
  __syncthreads();
  unsigned* hg = hist + (size_t)b * NBINS + lo_bin;
  for (int i = t; i < NBINS / 4; i += HB) {
    unsigned v = hl[i];
    unsigned clo = v & 0xFFFFu, chi = v >> 16;
    if (clo) atomicAdd(&hg[2 * i], clo);
    if (chi) atomicAdd(&hg[2 * i + 1], chi);
  }
}

// One block per batch: pick bin threshold so [T_lo, NBINS) holds ~TARGET
// candidates (<= CAP_C). Also zeroes cnt[b] for compact.
__global__ void __launch_bounds__(256) threshold_kernel(const unsigned* __restrict__ hist,
                                                        unsigned* __restrict__ T_lo,
                                                        unsigned* __restrict__ cnt) {
  const int BPT = NBINS / 256;  // 256 bins/thread, contiguous ownership
  __shared__ unsigned s_part[256];
  __shared__ unsigned s_T;
  int b = blockIdx.x, t = threadIdx.x;
  const unsigned* h = hist + (size_t)b * NBINS;
  if (t == 0) { s_T = 0xFFFFFFFFu; cnt[b] = 0u; }
  unsigned mysum = 0;
  const uint4* h4 = (const uint4*)(h + t * BPT);
  for (int k = 0; k < BPT / 4; ++k) {
    int bin0 = t * BPT + k * 4;
    if (bin0 >= 128) {  // bin>=128 <=> finite score; 128 % 4 == 0
      uint4 v = h4[k];
      mysum += v.x + v.y + v.z + v.w;
    }
  }
  s_part[t] = mysum;
  __syncthreads();
  for (int d = 1; d < 256; d <<= 1) {  // inclusive suffix sum
    unsigned v = (t + d < 256) ? s_part[t + d] : 0u;
    __syncthreads();
    s_part[t] += v;
    __syncthreads();
  }
  unsigned total = s_part[0];
  unsigned target = (TARGET < total) ? TARGET : total;
  unsigned above = (t + 1 < 256) ? s_part[t + 1] : 0u;
  if (total > 0u && above < target && s_part[t] >= target) {  // unique crossing thread
    unsigned c = above;
    for (int k = BPT - 1; k >= 0; --k) {
      unsigned bin = (unsigned)(t * BPT + k);
      if (bin < 128u) break;
      unsigned hv = h[bin];
      c += hv;
      if (c >= target) {
        unsigned T = bin;
        if (c > CAP_C && (c - hv) > 0u) T = bin + 1u;  // never overflow CAP_C
        s_T = T;
        break;
      }
    }
  }
  __syncthreads();
  if (t == 0) T_lo[b] = (total == 0u) ? 0xFFFFFFFFu : s_T;
}

// Full-GPU grid: append candidates above threshold to per-batch list.
__global__ void compact_kernel(const unsigned* __restrict__ keys,
                               const unsigned* __restrict__ T_lo,
                               u64* __restrict__ cand,
                               unsigned* __restrict__ cnt, int N) {
  int b = blockIdx.y;
  int i = blockIdx.x * blockDim.x + threadIdx.x;
  if (i >= N) return;
  unsigned u = keys[(size_t)b * N + i];
  if ((u >> 16) >= T_lo[b]) {
    unsigned p = atomicAdd(&cnt[b], 1u);
    if (p < CAP_C)  // ~i: argmax lowest-index tie-break after descending sort
      cand[(size_t)b * CAP_C + p] = ((u64)u << 32) | (unsigned)(~i);
  }
}

// One block per batch: bitonic sort CAP_C keys descending, gather sorted boxes.
__global__ void __launch_bounds__(1024) sort_kernel(const u64* __restrict__ cand,
                                                    const unsigned* __restrict__ cntp,
                                                    const float4* __restrict__ boxes,
                                                    float4* __restrict__ sboxes,
                                                    float* __restrict__ sscore,
                                                    int N) {
  __shared__ u64 sk[CAP_C];  // 16 KB
  int b = blockIdx.x, t = threadIdx.x;
  int cnt = (int)cntp[b];
  if (cnt > CAP_C) cnt = CAP_C;
  for (int i = t; i < CAP_C; i += 1024)
    sk[i] = (i < cnt) ? cand[(size_t)b * CAP_C + i] : 0ull;  // pad sinks to end
  __syncthreads();
  for (unsigned kk = 2; kk <= CAP_C; kk <<= 1) {
    for (unsigned j = kk >> 1; j >= 1u; j >>= 1) {
      unsigned pid = (unsigned)t;  // exactly CAP_C/2 pairs
      unsigned i = ((pid & ~(j - 1u)) << 1) | (pid & (j - 1u));
      unsigned p = i | j;
      u64 va = sk[i], vb = sk[p];
      bool up = ((i & kk) == 0u);
      bool sw = up ? (va < vb) : (va > vb);
      if (sw) { sk[i] = vb; sk[p] = va; }
      __syncthreads();
    }
  }
  for (int i = t; i < CAP_C; i += 1024) {
    u64 key = sk[i];
    float4 bx = make_float4(0.f, 0.f, 0.f, 0.f);
    float sc = -__builtin_inff();
    if (i < cnt) {
      unsigned idx = ~(unsigned)(key & 0xFFFFFFFFull);
      bx = boxes[(size_t)b * N + idx];
      unsigned u = (unsigned)(key >> 32);
      unsigned sb2 = (u & 0x80000000u) ? (u ^ 0x80000000u) : ~u;
      sc = __uint_as_float(sb2);
    }
    sboxes[(size_t)b * CAP_C + i] = bx;
    sscore[(size_t)b * CAP_C + i] = sc;
  }
}

// Pairwise suppression masks: bit l of word w in row i <=> IoU(i, 64w+l) > 0.7.
// Pad rows (zero boxes) produce all-zero rows/columns (inter=0 -> iou=0).
__global__ void __launch_bounds__(256) mask_kernel(const float4* __restrict__ sboxes,
                                                   u64* __restrict__ mask) {
#pragma clang fp contract(off)
  __shared__ float4 sb[CAP_C];  // 32 KB
  int b = blockIdx.y, t = threadIdx.x;
  int wave = t >> 6, lane = t & 63;
  const float4* src = sboxes + (size_t)b * CAP_C;
  for (int i = t; i < CAP_C; i += 256) sb[i] = src[i];
  __syncthreads();
  for (int r = 0; r < MROWS; ++r) {
    int row = blockIdx.x * MROWS + r;
    float4 rb = sb[row];                       // broadcast read
    float ra = (rb.z - rb.x) * (rb.w - rb.y);  // picked-box area (barea)
    for (int chunk = wave; chunk < NW; chunk += 4) {
      float4 cb = sb[chunk * 64 + lane];
      float ix1 = fmaxf(rb.x, cb.x), iy1 = fmaxf(rb.y, cb.y);
      float ix2 = fminf(rb.z, cb.z), iy2 = fminf(rb.w, cb.w);
      float inter = fmaxf(ix2 - ix1, 0.0f) * fmaxf(iy2 - iy1, 0.0f);
      float ca = (cb.z - cb.x) * (cb.w - cb.y);
      float iou = inter / (ra + ca - inter + 1e-9f);
      u64 bal = __ballot(iou > 0.7f);
      if (lane == 0)
        mask[((size_t)b * CAP_C + row) * NW + chunk] = bal;
    }
  }
}

// ---- Walk: serial greedy over the bitmask, with a MANUALLY SCALARIZED
// double-buffered register pipeline. Rounds 2/4 showed the compiler demotes
// any rolling pf[] array to scratch (VGPR_Count 40/32), putting ~190cyc of
// scratch latency in the serial chain. Named ulonglong4 variables + fully
// macro-unrolled straight-line loads/steps cannot be demoted.
// __launch_bounds__(64,1): 1 wave/EU -> 512-VGPR budget for ~290 live regs.

#define LD1(R) (ow ? Ml[(size_t)(((R) < CAP_C) ? (R) : (CAP_C - 1)) * NW] : 0ull)
#define LD4(V, R) V.x = LD1(R); V.y = LD1((R) + 1); V.z = LD1((R) + 2); V.w = LD1((R) + 3);
#define LOAD(p, R) \
  LD4(p##0, (R) + 0)  LD4(p##1, (R) + 4)  LD4(p##2, (R) + 8)  LD4(p##3, (R) + 12) \
  LD4(p##4, (R) + 16) LD4(p##5, (R) + 20) LD4(p##6, (R) + 24) LD4(p##7, (R) + 28) \
  LD4(p##8, (R) + 32) LD4(p##9, (R) + 36) LD4(p##10, (R) + 40) LD4(p##11, (R) + 44) \
  LD4(p##12, (R) + 48) LD4(p##13, (R) + 52) LD4(p##14, (R) + 56) LD4(p##15, (R) + 60)

// One candidate. BASE is 64-aligned -> (I)&63 is a compile-time constant,
// (I)>>6 is wave-uniform. Decisions wave-uniform (ballot) -> nk uniform.
#define STEP(MV, I) { \
  const int i_ = (I); \
  u64 mybit_ = (lane == (i_ >> 6)) ? ((removed >> (i_ & 63)) & 1ull) : 0ull; \
  bool sup_ = __any((int)mybit_); \
  if (!sup_ && (i_ < cnt) && (nk < K)) { \
    removed |= (MV); \
    if (lane == 0) s_keep[nk] = i_; \
    ++nk; \
  } \
}
#define ST4(V, I) STEP(V.x, (I)) STEP(V.y, (I) + 1) STEP(V.z, (I) + 2) STEP(V.w, (I) + 3)
#define CONSUME(p, BB) \
  ST4(p##0, (BB) + 0)  ST4(p##1, (BB) + 4)  ST4(p##2, (BB) + 8)  ST4(p##3, (BB) + 12) \
  ST4(p##4, (BB) + 16) ST4(p##5, (BB) + 20) ST4(p##6, (BB) + 24) ST4(p##7, (BB) + 28) \
  ST4(p##8, (BB) + 32) ST4(p##9, (BB) + 36) ST4(p##10, (BB) + 40) ST4(p##11, (BB) + 44) \
  ST4(p##12, (BB) + 48) ST4(p##13, (BB) + 52) ST4(p##14, (BB) + 56) ST4(p##15, (BB) + 60)
#define DECL(p) ulonglong4 p##0, p##1, p##2, p##3, p##4, p##5, p##6, p##7, \
                          p##8, p##9, p##10, p##11, p##12, p##13, p##14, p##15;

__global__ void __launch_bounds__(64, 1) walk_kernel(const u64* __restrict__ mask,
                                                     const float4* __restrict__ sboxes,
                                                     const float* __restrict__ sscore,
                                                     const unsigned* __restrict__ cntp,
                                                     float* __restrict__ out, int K) {
  __shared__ int s_keep[KMAX];
  int b = blockIdx.x, lane = threadIdx.x;
  const u64* M = mask + (size_t)b * CAP_C * NW;
  int cnt = (int)cntp[b];
  if (cnt > CAP_C) cnt = CAP_C;
  const bool ow = lane < NW;
  const u64* Ml = M + lane;  // lane's word column
  u64 removed = 0ull;
  int nk = 0;
  DECL(A)
  DECL(B)
  int base = 0;
  LOAD(A, 0)
  for (int c2 = 0; c2 < CAP_C / 128; ++c2) {
    LOAD(B, base + 64)      // prefetch next chunk (indep of decisions)
    CONSUME(A, base)        // 64 straight-line steps, loads off-chain
    base += 64;
    if (base >= cnt || nk >= K) break;
    LOAD(A, base + 64)
    CONSUME(B, base)
    base += 64;
    if (base >= cnt || nk >= K) break;
  }
  __syncthreads();
  for (int j = lane; j < nk; j += 64) {
    int i = s_keep[j];
    float4 bx = sboxes[(size_t)b * CAP_C + i];
    float sc = sscore[(size_t)b * CAP_C + i];
    float* row = out + ((size_t)b * K + j) * 6;
    row[0] = bx.x; row[1] = bx.y; row[2] = bx.z; row[3] = bx.w;
    row[4] = sc; row[5] = 1.0f;
  }
  for (int j = nk + lane; j < K; j += 64) {  // zero invalid tail rows
    float* row = out + ((size_t)b * K + j) * 6;
    row[0] = 0.f; row[1] = 0.f; row[2] = 0.f; row[3] = 0.f;
    row[4] = 0.f; row[5] = 0.f;
  }
}

extern "C" void kernel_launch(void* const* d_in, const int* in_sizes, int n_in,
                              void* d_out, int out_size, void* d_ws, size_t ws_size,
                              hipStream_t stream) {
  const float4* anchors = (const float4*)d_in[0];
  const float4* deltas = (const float4*)d_in[1];
  const float* obj = (const float*)d_in[2];
  const int* imh = (const int*)d_in[3];
  const int* imw = (const int*)d_in[4];
  int N = in_sizes[0] / 4;
  int B = in_sizes[2] / N;
  int K = out_size / (B * 6);
  if (K > KMAX) K = KMAX;

  // ws layout (alignment-descending)
  char* ws = (char*)d_ws;
  size_t off = 0;
  float4* boxes = (float4*)(ws + off);            off += (size_t)B * N * 16;
  float4* sboxes = (float4*)(ws + off);           off += (size_t)B * CAP_C * 16;
  u64* cand = (u64*)(ws + off);                   off += (size_t)B * CAP_C * 8;
  u64* mask = (u64*)(ws + off);                   off += (size_t)B * CAP_C * NW * 8;
  unsigned* keys = (unsigned*)(ws + off);         off += (size_t)B * N * 4;
  unsigned* hist = (unsigned*)(ws + off);         off += (size_t)B * NBINS * 4;
  float* sscore = (float*)(ws + off);             off += (size_t)B * CAP_C * 4;
  unsigned* T_lo = (unsigned*)(ws + off);         off += (size_t)B * 4;
  unsigned* cnt = (unsigned*)(ws + off);          off += (size_t)B * 4;
  float* out = (float*)d_out;

  int nb = (N + 255) / 256;
  int P = (N + HE - 1) / HE;
  decode_kernel<<<nb, 256, 0, stream>>>(anchors, deltas, obj, imh, imw,
                                        boxes, keys, hist, N, B);
  hist_kernel<<<dim3(P, 2, B), HB, 0, stream>>>(keys, hist, N);
  threshold_kernel<<<B, 256, 0, stream>>>(hist, T_lo, cnt);
  compact_kernel<<<dim3(nb, B), 256, 0, stream>>>(keys, T_lo, cand, cnt, N);
  sort_kernel<<<B, 1024, 0, stream>>>(cand, cnt, boxes, sboxes, sscore, N);
  mask_kernel<<<dim3(CAP_C / MROWS, B), 256, 0, stream>>>(sboxes, mask);
  walk_kernel<<<B, 64, 0, stream>>>(mask, sboxes, sscore, cnt, out, K);
}

// Round 6
// 312.714 us; speedup vs baseline: 4.3375x; 1.1477x over previous
//
#include <hip/hip_runtime.h>
#include <cstdint>
#include <cstddef>

#define NBINS 65536         // 16-bit histogram of orderable score
#define CAP_C 2048          // candidate pool (pow2, = sort size)
#define NW (CAP_C / 64)     // 64-bit mask words per row = 32
#define TARGET 1792u        // threshold target (headroom to CAP_C)
#define KMAX 1008           // kept-list capacity
#define MROWS 16            // rows per mask block
#define HB 1024             // hist block threads
#define HE 32768            // keys per hist block (16-bit pack: counts <= HE < 65536)

typedef unsigned long long u64;

__device__ __forceinline__ unsigned orderable(float f) {
  unsigned b = __float_as_uint(f);
  return (b & 0x80000000u) ? ~b : (b | 0x80000000u);
}

// Pure streaming: also zero-fills hist (no separate init dispatch).
__global__ void decode_kernel(const float4* __restrict__ anchors,
                              const float4* __restrict__ deltas,
                              const float* __restrict__ obj,
                              const int* __restrict__ im_h_p,
                              const int* __restrict__ im_w_p,
                              float4* __restrict__ boxes,
                              unsigned* __restrict__ keys,
                              unsigned* __restrict__ hist,
                              int N, int B) {
#pragma clang fp contract(off)
  int n = blockIdx.x * blockDim.x + threadIdx.x;
  int stride = gridDim.x * blockDim.x;
  for (int j = n; j < B * NBINS; j += stride) hist[j] = 0u;
  if (n >= N) return;
  float imw = (float)(*im_w_p);
  float imh = (float)(*im_h_p);
  float4 a = anchors[n];
  float aw = a.z - a.x;
  float ah = a.w - a.y;
  float acx = a.x + 0.5f * aw;
  float acy = a.y + 0.5f * ah;
  const float LOGM = 4.135166556742356f;  // log(1000/16) rounded to f32
  for (int b = 0; b < B; ++b) {
    size_t off = (size_t)b * N + n;
    float4 d = deltas[off];
    float dw = fminf(d.z, LOGM), dh = fminf(d.w, LOGM);
    float pcx = d.x * aw + acx;
    float pcy = d.y * ah + acy;
    float pw = expf(dw) * aw;
    float ph = expf(dh) * ah;
    float x1 = fminf(fmaxf(pcx - 0.5f * pw, 0.0f), imw);
    float y1 = fminf(fmaxf(pcy - 0.5f * ph, 0.0f), imh);
    float x2 = fminf(fmaxf(pcx + 0.5f * pw, 0.0f), imw);
    float y2 = fminf(fmaxf(pcy + 0.5f * ph, 0.0f), imh);
    boxes[off] = make_float4(x1, y1, x2, y2);
    float area = (x2 - x1) * (y2 - y1);
    float sc = (area > 1.0f) ? obj[off] : -__builtin_inff();
    keys[off] = orderable(sc);
  }
}

// LDS-privatized histogram (round-4 win: killed 140us of contended atomics).
__global__ void __launch_bounds__(HB) hist_kernel(const unsigned* __restrict__ keys,
                                                  unsigned* __restrict__ hist,
                                                  int N) {
  __shared__ unsigned hl[NBINS / 4];  // 16384 uints = 64 KB
  int t = threadIdx.x;
  int half = blockIdx.y, b = blockIdx.z;
  unsigned lo_bin = (unsigned)half * 32768u;
  for (int i = t; i < NBINS / 4; i += HB) hl[i] = 0u;
  __syncthreads();
  const unsigned* kb = keys + (size_t)b * N;
  int base = blockIdx.x * HE;
  int end = base + HE;
  if (end > N) end = N;
  for (int i = base + t; i < end; i += HB) {
    unsigned bin = kb[i] >> 16;
    unsigned lb = bin - lo_bin;
    if (lb < 32768u)
      atomicAdd(&hl[lb >> 1], (lb & 1u) ? 65536u : 1u);
  }
  __syncthreads();
  unsigned* hg = hist + (size_t)b * NBINS + lo_bin;
  for (int i = t; i < NBINS / 4; i += HB) {
    unsigned v = hl[i];
    unsigned clo = v & 0xFFFFu, chi = v >> 16;
    if (clo) atomicAdd(&hg[2 * i], clo);
    if (chi) atomicAdd(&hg[2 * i + 1], chi);
  }
}

// One block per batch: pick bin threshold so [T_lo, NBINS) holds ~TARGET
// candidates (<= CAP_C). Also zeroes cnt[b] for compact.
__global__ void __launch_bounds__(256) threshold_kernel(const unsigned* __restrict__ hist,
                                                        unsigned* __restrict__ T_lo,
                                                        unsigned* __restrict__ cnt) {
  const int BPT = NBINS / 256;  // 256 bins/thread, contiguous ownership
  __shared__ unsigned s_part[256];
  __shared__ unsigned s_T;
  int b = blockIdx.x, t = threadIdx.x;
  const unsigned* h = hist + (size_t)b * NBINS;
  if (t == 0) { s_T = 0xFFFFFFFFu; cnt[b] = 0u; }
  unsigned mysum = 0;
  const uint4* h4 = (const uint4*)(h + t * BPT);
  for (int k = 0; k < BPT / 4; ++k) {
    int bin0 = t * BPT + k * 4;
    if (bin0 >= 128) {  // bin>=128 <=> finite score; 128 % 4 == 0
      uint4 v = h4[k];
      mysum += v.x + v.y + v.z + v.w;
    }
  }
  s_part[t] = mysum;
  __syncthreads();
  for (int d = 1; d < 256; d <<= 1) {  // inclusive suffix sum
    unsigned v = (t + d < 256) ? s_part[t + d] : 0u;
    __syncthreads();
    s_part[t] += v;
    __syncthreads();
  }
  unsigned total = s_part[0];
  unsigned target = (TARGET < total) ? TARGET : total;
  unsigned above = (t + 1 < 256) ? s_part[t + 1] : 0u;
  if (total > 0u && above < target && s_part[t] >= target) {  // unique crossing thread
    unsigned c = above;
    for (int k = BPT - 1; k >= 0; --k) {
      unsigned bin = (unsigned)(t * BPT + k);
      if (bin < 128u) break;
      unsigned hv = h[bin];
      c += hv;
      if (c >= target) {
        unsigned T = bin;
        if (c > CAP_C && (c - hv) > 0u) T = bin + 1u;  // never overflow CAP_C
        s_T = T;
        break;
      }
    }
  }
  __syncthreads();
  if (t == 0) T_lo[b] = (total == 0u) ? 0xFFFFFFFFu : s_T;
}

// Full-GPU grid: append candidates above threshold to per-batch list.
__global__ void compact_kernel(const unsigned* __restrict__ keys,
                               const unsigned* __restrict__ T_lo,
                               u64* __restrict__ cand,
                               unsigned* __restrict__ cnt, int N) {
  int b = blockIdx.y;
  int i = blockIdx.x * blockDim.x + threadIdx.x;
  if (i >= N) return;
  unsigned u = keys[(size_t)b * N + i];
  if ((u >> 16) >= T_lo[b]) {
    unsigned p = atomicAdd(&cnt[b], 1u);
    if (p < CAP_C)  // ~i: argmax lowest-index tie-break after descending sort
      cand[(size_t)b * CAP_C + p] = ((u64)u << 32) | (unsigned)(~i);
  }
}

// One block per batch: bitonic sort CAP_C keys descending, gather sorted boxes.
__global__ void __launch_bounds__(1024) sort_kernel(const u64* __restrict__ cand,
                                                    const unsigned* __restrict__ cntp,
                                                    const float4* __restrict__ boxes,
                                                    float4* __restrict__ sboxes,
                                                    float* __restrict__ sscore,
                                                    int N) {
  __shared__ u64 sk[CAP_C];  // 16 KB
  int b = blockIdx.x, t = threadIdx.x;
  int cnt = (int)cntp[b];
  if (cnt > CAP_C) cnt = CAP_C;
  for (int i = t; i < CAP_C; i += 1024)
    sk[i] = (i < cnt) ? cand[(size_t)b * CAP_C + i] : 0ull;  // pad sinks to end
  __syncthreads();
  for (unsigned kk = 2; kk <= CAP_C; kk <<= 1) {
    for (unsigned j = kk >> 1; j >= 1u; j >>= 1) {
      unsigned pid = (unsigned)t;  // exactly CAP_C/2 pairs
      unsigned i = ((pid & ~(j - 1u)) << 1) | (pid & (j - 1u));
      unsigned p = i | j;
      u64 va = sk[i], vb = sk[p];
      bool up = ((i & kk) == 0u);
      bool sw = up ? (va < vb) : (va > vb);
      if (sw) { sk[i] = vb; sk[p] = va; }
      __syncthreads();
    }
  }
  for (int i = t; i < CAP_C; i += 1024) {
    u64 key = sk[i];
    float4 bx = make_float4(0.f, 0.f, 0.f, 0.f);
    float sc = -__builtin_inff();
    if (i < cnt) {
      unsigned idx = ~(unsigned)(key & 0xFFFFFFFFull);
      bx = boxes[(size_t)b * N + idx];
      unsigned u = (unsigned)(key >> 32);
      unsigned sb2 = (u & 0x80000000u) ? (u ^ 0x80000000u) : ~u;
      sc = __uint_as_float(sb2);
    }
    sboxes[(size_t)b * CAP_C + i] = bx;
    sscore[(size_t)b * CAP_C + i] = sc;
  }
}

// Pairwise suppression masks: bit l of word w in row i <=> IoU(i, 64w+l) > 0.7.
// Pad rows (zero boxes) produce all-zero rows/columns (inter=0 -> iou=0).
__global__ void __launch_bounds__(256) mask_kernel(const float4* __restrict__ sboxes,
                                                   u64* __restrict__ mask) {
#pragma clang fp contract(off)
  __shared__ float4 sb[CAP_C];  // 32 KB
  int b = blockIdx.y, t = threadIdx.x;
  int wave = t >> 6, lane = t & 63;
  const float4* src = sboxes + (size_t)b * CAP_C;
  for (int i = t; i < CAP_C; i += 256) sb[i] = src[i];
  __syncthreads();
  for (int r = 0; r < MROWS; ++r) {
    int row = blockIdx.x * MROWS + r;
    float4 rb = sb[row];                       // broadcast read
    float ra = (rb.z - rb.x) * (rb.w - rb.y);  // picked-box area (barea)
    for (int chunk = wave; chunk < NW; chunk += 4) {
      float4 cb = sb[chunk * 64 + lane];
      float ix1 = fmaxf(rb.x, cb.x), iy1 = fmaxf(rb.y, cb.y);
      float ix2 = fminf(rb.z, cb.z), iy2 = fminf(rb.w, cb.w);
      float inter = fmaxf(ix2 - ix1, 0.0f) * fmaxf(iy2 - iy1, 0.0f);
      float ca = (cb.z - cb.x) * (cb.w - cb.y);
      float iou = inter / (ra + ca - inter + 1e-9f);
      u64 bal = __ballot(iou > 0.7f);
      if (lane == 0)
        mask[((size_t)b * CAP_C + row) * NW + chunk] = bal;
    }
  }
}

// ---- Walk v3: tile-resolve + data-parallel apply.
// Rounds 2/4/5 lesson: any per-candidate serial chain that touches memory
// (even "prefetched") ends up latency-bound because the compiler won't keep
// a deep pipeline live across a 64-step dependent chain. So: restructure.
// Per 64-candidate tile (base 64-aligned):
//   - all 64 candidates' "already removed" bits live in ONE lane's `removed`
//     word (lane = base>>6): one readlane -> uniform in_rm.
//   - within-tile greedy = wave-uniform SCALAR loop over keeps only:
//     ctz(pend) -> readlane(D, j) (diagonal 64x64 tile word, prefetched one
//     tile ahead) -> pend &= ~row. No memory in the chain.
//   - apply: 64 named u64 regs C0..C63 = the tile's full mask rows (loads
//     issued BEFORE the resolve; one amortized vmcnt per tile);
//     removed |= Cn & -(keep>>n&1): 64 independent AND/ORs, off-chain.
// Lanes >= NW hold garbage in C/removed; never read (readlane only < NW).

#define X64(F) F(0) F(1) F(2) F(3) F(4) F(5) F(6) F(7) F(8) F(9) F(10) F(11) \
  F(12) F(13) F(14) F(15) F(16) F(17) F(18) F(19) F(20) F(21) F(22) F(23) \
  F(24) F(25) F(26) F(27) F(28) F(29) F(30) F(31) F(32) F(33) F(34) F(35) \
  F(36) F(37) F(38) F(39) F(40) F(41) F(42) F(43) F(44) F(45) F(46) F(47) \
  F(48) F(49) F(50) F(51) F(52) F(53) F(54) F(55) F(56) F(57) F(58) F(59) \
  F(60) F(61) F(62) F(63)

#define CDC(n) u64 C##n;
#define CLD(n) C##n = Mr[(size_t)(n) * NW];
#define CAP(n) acc |= C##n & ((u64)0 - ((keep >> (n)) & 1ull));

__global__ void __launch_bounds__(64, 1) walk_kernel(const u64* __restrict__ mask,
                                                     const float4* __restrict__ sboxes,
                                                     const float* __restrict__ sscore,
                                                     const unsigned* __restrict__ cntp,
                                                     float* __restrict__ out, int K) {
  __shared__ int s_keep[KMAX];
  const int b = blockIdx.x;
  const int lane = threadIdx.x;
  const u64* M = mask + (size_t)b * CAP_C * NW;
  int cnt = (int)cntp[b];
  if (cnt > CAP_C) cnt = CAP_C;
  u64 removed = 0ull;
  int nk = 0;
  CDC(0) CDC(1) CDC(2) CDC(3) CDC(4) CDC(5) CDC(6) CDC(7)
  CDC(8) CDC(9) CDC(10) CDC(11) CDC(12) CDC(13) CDC(14) CDC(15)
  CDC(16) CDC(17) CDC(18) CDC(19) CDC(20) CDC(21) CDC(22) CDC(23)
  CDC(24) CDC(25) CDC(26) CDC(27) CDC(28) CDC(29) CDC(30) CDC(31)
  CDC(32) CDC(33) CDC(34) CDC(35) CDC(36) CDC(37) CDC(38) CDC(39)
  CDC(40) CDC(41) CDC(42) CDC(43) CDC(44) CDC(45) CDC(46) CDC(47)
  CDC(48) CDC(49) CDC(50) CDC(51) CDC(52) CDC(53) CDC(54) CDC(55)
  CDC(56) CDC(57) CDC(58) CDC(59) CDC(60) CDC(61) CDC(62) CDC(63)

  // tile-0 diagonal: lane j holds M[j][0]
  u64 D = M[(size_t)lane * NW];
  int base = 0;
  for (int t = 0; t < CAP_C / 64; ++t) {
    const u64* Mr = M + (size_t)base * NW + lane;
    X64(CLD)  // issue all 64 row loads (first use is the apply, after resolve)
    // prefetch next tile's diagonal (clamped; last-iter value unused)
    int nb2 = (base + 64 < CAP_C) ? (base + 64) : base;
    u64 Dn = M[((size_t)nb2 + lane) * NW + (size_t)(nb2 >> 6)];

    // ---- resolve (wave-uniform scalar loop; D from previous iteration)
    unsigned tl = (unsigned)(base >> 6);
    unsigned rlo = __builtin_amdgcn_readlane((unsigned)(removed & 0xFFFFFFFFull), tl);
    unsigned rhi = __builtin_amdgcn_readlane((unsigned)(removed >> 32), tl);
    u64 in_rm = ((u64)rhi << 32) | (u64)rlo;
    int rem = cnt - base;
    u64 valid = (rem >= 64) ? ~0ull : ((rem <= 0) ? 0ull : ((1ull << rem) - 1ull));
    u64 pend = (~in_rm) & valid;
    u64 keep = 0ull;
    int nk0 = nk;
    while (pend != 0ull && nk < K) {
      int j = __builtin_ctzll(pend);       // ascending index = greedy order
      keep |= (1ull << j);
      ++nk;
      unsigned dlo = __builtin_amdgcn_readlane((unsigned)(D & 0xFFFFFFFFull), j);
      unsigned dhi = __builtin_amdgcn_readlane((unsigned)(D >> 32), j);
      u64 row = ((u64)dhi << 32) | (u64)dlo;
      pend &= ~row;                        // within-tile suppression
      pend &= ~(1ull << j);
    }

    // ---- record keeps (parallel; position by popcount prefix)
    if ((keep >> lane) & 1ull)
      s_keep[nk0 + __popcll(keep & ((1ull << lane) - 1ull))] = base + lane;

    // ---- apply: OR kept rows into removed (independent, reassociable)
    u64 acc = 0ull;
    X64(CAP)
    removed |= acc;

    D = Dn;
    base += 64;
    if (base >= cnt || nk >= K) break;
  }
  __syncthreads();
  for (int j = lane; j < nk; j += 64) {
    int i = s_keep[j];
    float4 bx = sboxes[(size_t)b * CAP_C + i];
    float sc = sscore[(size_t)b * CAP_C + i];
    float* row = out + ((size_t)b * K + j) * 6;
    row[0] = bx.x; row[1] = bx.y; row[2] = bx.z; row[3] = bx.w;
    row[4] = sc; row[5] = 1.0f;
  }
  for (int j = nk + lane; j < K; j += 64) {  // zero invalid tail rows
    float* row = out + ((size_t)b * K + j) * 6;
    row[0] = 0.f; row[1] = 0.f; row[2] = 0.f; row[3] = 0.f;
    row[4] = 0.f; row[5] = 0.f;
  }
}

extern "C" void kernel_launch(void* const* d_in, const int* in_sizes, int n_in,
                              void* d_out, int out_size, void* d_ws, size_t ws_size,
                              hipStream_t stream) {
  const float4* anchors = (const float4*)d_in[0];
  const float4* deltas = (const float4*)d_in[1];
  const float* obj = (const float*)d_in[2];
  const int* imh = (const int*)d_in[3];
  const int* imw = (const int*)d_in[4];
  int N = in_sizes[0] / 4;
  int B = in_sizes[2] / N;
  int K = out_size / (B * 6);
  if (K > KMAX) K = KMAX;

  // ws layout (alignment-descending). NOTE: keys must follow mask (walk's
  // lanes>=NW over-read <=248B past a row; must stay inside ws).
  char* ws = (char*)d_ws;
  size_t off = 0;
  float4* boxes = (float4*)(ws + off);            off += (size_t)B * N * 16;
  float4* sboxes = (float4*)(ws + off);           off += (size_t)B * CAP_C * 16;
  u64* cand = (u64*)(ws + off);                   off += (size_t)B * CAP_C * 8;
  u64* mask = (u64*)(ws + off);                   off += (size_t)B * CAP_C * NW * 8;
  unsigned* keys = (unsigned*)(ws + off);         off += (size_t)B * N * 4;
  unsigned* hist = (unsigned*)(ws + off);         off += (size_t)B * NBINS * 4;
  float* sscore = (float*)(ws + off);             off += (size_t)B * CAP_C * 4;
  unsigned* T_lo = (unsigned*)(ws + off);         off += (size_t)B * 4;
  unsigned* cnt = (unsigned*)(ws + off);          off += (size_t)B * 4;
  float* out = (float*)d_out;

  int nb = (N + 255) / 256;
  int P = (N + HE - 1) / HE;
  decode_kernel<<<nb, 256, 0, stream>>>(anchors, deltas, obj, imh, imw,
                                        boxes, keys, hist, N, B);
  hist_kernel<<<dim3(P, 2, B), HB, 0, stream>>>(keys, hist, N);
  threshold_kernel<<<B, 256, 0, stream>>>(hist, T_lo, cnt);
  compact_kernel<<<dim3(nb, B), 256, 0, stream>>>(keys, T_lo, cand, cnt, N);
  sort_kernel<<<B, 1024, 0, stream>>>(cand, cnt, boxes, sboxes, sscore, N);
  mask_kernel<<<dim3(CAP_C / MROWS, B), 256, 0, stream>>>(sboxes, mask);
  walk_kernel<<<B, 64, 0, stream>>>(mask, sboxes, sscore, cnt, out, K);
}

// Round 7
// 245.098 us; speedup vs baseline: 5.5340x; 1.2759x over previous
//
#include <hip/hip_runtime.h>
#include <cstdint>
#include <cstddef>

#define NBINS 65536         // 16-bit histogram of orderable score
#define CAP_C 2048          // candidate pool (pow2, = sort size)
#define NW (CAP_C / 64)     // 64-bit mask words per row = 32
#define TARGET 1792u        // threshold target (headroom to CAP_C)
#define KMAX 1008           // kept-list capacity
#define MROWS 16            // rows per mask block
#define HB 1024             // hist block threads
#define HE 32768            // keys per hist block (16-bit pack: counts <= HE < 65536)
#define CNT_STRIDE 64       // cnt[b*64]: 256B per counter, no shared lines
#define CPB 64              // compact blocks per batch

typedef unsigned long long u64;

__device__ __forceinline__ unsigned orderable(float f) {
  unsigned b = __float_as_uint(f);
  return (b & 0x80000000u) ? ~b : (b | 0x80000000u);
}

// Pure streaming: also zero-fills hist (no separate init dispatch).
__global__ void decode_kernel(const float4* __restrict__ anchors,
                              const float4* __restrict__ deltas,
                              const float* __restrict__ obj,
                              const int* __restrict__ im_h_p,
                              const int* __restrict__ im_w_p,
                              float4* __restrict__ boxes,
                              unsigned* __restrict__ keys,
                              unsigned* __restrict__ hist,
                              int N, int B) {
#pragma clang fp contract(off)
  int n = blockIdx.x * blockDim.x + threadIdx.x;
  int stride = gridDim.x * blockDim.x;
  for (int j = n; j < B * NBINS; j += stride) hist[j] = 0u;
  if (n >= N) return;
  float imw = (float)(*im_w_p);
  float imh = (float)(*im_h_p);
  float4 a = anchors[n];
  float aw = a.z - a.x;
  float ah = a.w - a.y;
  float acx = a.x + 0.5f * aw;
  float acy = a.y + 0.5f * ah;
  const float LOGM = 4.135166556742356f;  // log(1000/16) rounded to f32
  for (int b = 0; b < B; ++b) {
    size_t off = (size_t)b * N + n;
    float4 d = deltas[off];
    float dw = fminf(d.z, LOGM), dh = fminf(d.w, LOGM);
    float pcx = d.x * aw + acx;
    float pcy = d.y * ah + acy;
    float pw = expf(dw) * aw;
    float ph = expf(dh) * ah;
    float x1 = fminf(fmaxf(pcx - 0.5f * pw, 0.0f), imw);
    float y1 = fminf(fmaxf(pcy - 0.5f * ph, 0.0f), imh);
    float x2 = fminf(fmaxf(pcx + 0.5f * pw, 0.0f), imw);
    float y2 = fminf(fmaxf(pcy + 0.5f * ph, 0.0f), imh);
    boxes[off] = make_float4(x1, y1, x2, y2);
    float area = (x2 - x1) * (y2 - y1);
    float sc = (area > 1.0f) ? obj[off] : -__builtin_inff();
    keys[off] = orderable(sc);
  }
}

// LDS-privatized histogram (round-4 win: killed 140us of contended atomics).
__global__ void __launch_bounds__(HB) hist_kernel(const unsigned* __restrict__ keys,
                                                  unsigned* __restrict__ hist,
                                                  int N) {
  __shared__ unsigned hl[NBINS / 4];  // 16384 uints = 64 KB
  int t = threadIdx.x;
  int half = blockIdx.y, b = blockIdx.z;
  unsigned lo_bin = (unsigned)half * 32768u;
  for (int i = t; i < NBINS / 4; i += HB) hl[i] = 0u;
  __syncthreads();
  const unsigned* kb = keys + (size_t)b * N;
  int base = blockIdx.x * HE;
  int end = base + HE;
  if (end > N) end = N;
  for (int i = base + t; i < end; i += HB) {
    unsigned bin = kb[i] >> 16;
    unsigned lb = bin - lo_bin;
    if (lb < 32768u)
      atomicAdd(&hl[lb >> 1], (lb & 1u) ? 65536u : 1u);
  }
  __syncthreads();
  unsigned* hg = hist + (size_t)b * NBINS + lo_bin;
  for (int i = t; i < NBINS / 4; i += HB) {
    unsigned v = hl[i];
    unsigned clo = v & 0xFFFFu, chi = v >> 16;
    if (clo) atomicAdd(&hg[2 * i], clo);
    if (chi) atomicAdd(&hg[2 * i + 1], chi);
  }
}

// One block per batch: pick bin threshold so [T_lo, NBINS) holds ~TARGET
// candidates (<= CAP_C). Also zeroes cnt[b*CNT_STRIDE] for compact.
__global__ void __launch_bounds__(256) threshold_kernel(const unsigned* __restrict__ hist,
                                                        unsigned* __restrict__ T_lo,
                                                        unsigned* __restrict__ cnt) {
  const int BPT = NBINS / 256;  // 256 bins/thread, contiguous ownership
  __shared__ unsigned s_part[256];
  __shared__ unsigned s_T;
  int b = blockIdx.x, t = threadIdx.x;
  const unsigned* h = hist + (size_t)b * NBINS;
  if (t == 0) { s_T = 0xFFFFFFFFu; cnt[b * CNT_STRIDE] = 0u; }
  unsigned mysum = 0;
  const uint4* h4 = (const uint4*)(h + t * BPT);
  for (int k = 0; k < BPT / 4; ++k) {
    int bin0 = t * BPT + k * 4;
    if (bin0 >= 128) {  // bin>=128 <=> finite score; 128 % 4 == 0
      uint4 v = h4[k];
      mysum += v.x + v.y + v.z + v.w;
    }
  }
  s_part[t] = mysum;
  __syncthreads();
  for (int d = 1; d < 256; d <<= 1) {  // inclusive suffix sum
    unsigned v = (t + d < 256) ? s_part[t + d] : 0u;
    __syncthreads();
    s_part[t] += v;
    __syncthreads();
  }
  unsigned total = s_part[0];
  unsigned target = (TARGET < total) ? TARGET : total;
  unsigned above = (t + 1 < 256) ? s_part[t + 1] : 0u;
  if (total > 0u && above < target && s_part[t] >= target) {  // unique crossing thread
    unsigned c = above;
    for (int k = BPT - 1; k >= 0; --k) {
      unsigned bin = (unsigned)(t * BPT + k);
      if (bin < 128u) break;
      unsigned hv = h[bin];
      c += hv;
      if (c >= target) {
        unsigned T = bin;
        if (c > CAP_C && (c - hv) > 0u) T = bin + 1u;  // never overflow CAP_C
        s_T = T;
        break;
      }
    }
  }
  __syncthreads();
  if (t == 0) T_lo[b] = (total == 0u) ? 0xFFFFFFFFu : s_T;
}

// compact v2: block-aggregated. Round-6: ~5500 wave atomics to 4 addresses in
// ONE L2 line (+ every block reading T_lo on that dirtied line) = 70us of
// line-ownership serialization. Now: LDS staging, ONE reservation atomic per
// block (64/batch), cnt padded to its own 256B line, coalesced writes.
// Order within cand[] is irrelevant: sort's total order on (score,~i) keys
// makes the final sequence deterministic.
__global__ void __launch_bounds__(1024) compact_kernel(const unsigned* __restrict__ keys,
                                                       const unsigned* __restrict__ T_lo,
                                                       u64* __restrict__ cand,
                                                       unsigned* __restrict__ cnt, int N) {
  __shared__ u64 s_w[4096];  // 32 KB winner staging (total/batch <= ~2048)
  __shared__ unsigned s_n, s_base;
  int b = blockIdx.y, t = threadIdx.x;
  if (t == 0) s_n = 0u;
  __syncthreads();
  unsigned T = T_lo[b];
  int slice = (N + CPB - 1) / CPB;
  int base = blockIdx.x * slice;
  int end = base + slice;
  if (end > N) end = N;
  const unsigned* kb = keys + (size_t)b * N;
  for (int i = base + t; i < end; i += 1024) {
    unsigned u = kb[i];
    if ((u >> 16) >= T) {
      unsigned p = atomicAdd(&s_n, 1u);
      if (p < 4096u)  // ~i: argmax lowest-index tie-break after descending sort
        s_w[p] = ((u64)u << 32) | (unsigned)(~i);
    }
  }
  __syncthreads();
  unsigned n = s_n < 4096u ? s_n : 4096u;
  if (t == 0) s_base = (n > 0u) ? atomicAdd(&cnt[b * CNT_STRIDE], n) : 0u;
  __syncthreads();
  unsigned gb = s_base;
  for (unsigned j = t; j < n; j += 1024) {
    unsigned p = gb + j;
    if (p < CAP_C) cand[(size_t)b * CAP_C + p] = s_w[j];
  }
}

// One block per batch: bitonic sort CAP_C keys descending, gather sorted boxes.
__global__ void __launch_bounds__(1024) sort_kernel(const u64* __restrict__ cand,
                                                    const unsigned* __restrict__ cntp,
                                                    const float4* __restrict__ boxes,
                                                    float4* __restrict__ sboxes,
                                                    float* __restrict__ sscore,
                                                    int N) {
  __shared__ u64 sk[CAP_C];  // 16 KB
  int b = blockIdx.x, t = threadIdx.x;
  int cnt = (int)cntp[b * CNT_STRIDE];
  if (cnt > CAP_C) cnt = CAP_C;
  for (int i = t; i < CAP_C; i += 1024)
    sk[i] = (i < cnt) ? cand[(size_t)b * CAP_C + i] : 0ull;  // pad sinks to end
  __syncthreads();
  for (unsigned kk = 2; kk <= CAP_C; kk <<= 1) {
    for (unsigned j = kk >> 1; j >= 1u; j >>= 1) {
      unsigned pid = (unsigned)t;  // exactly CAP_C/2 pairs
      unsigned i = ((pid & ~(j - 1u)) << 1) | (pid & (j - 1u));
      unsigned p = i | j;
      u64 va = sk[i], vb = sk[p];
      bool up = ((i & kk) == 0u);
      bool sw = up ? (va < vb) : (va > vb);
      if (sw) { sk[i] = vb; sk[p] = va; }
      __syncthreads();
    }
  }
  for (int i = t; i < CAP_C; i += 1024) {
    u64 key = sk[i];
    float4 bx = make_float4(0.f, 0.f, 0.f, 0.f);
    float sc = -__builtin_inff();
    if (i < cnt) {
      unsigned idx = ~(unsigned)(key & 0xFFFFFFFFull);
      bx = boxes[(size_t)b * N + idx];
      unsigned u = (unsigned)(key >> 32);
      unsigned sb2 = (u & 0x80000000u) ? (u ^ 0x80000000u) : ~u;
      sc = __uint_as_float(sb2);
    }
    sboxes[(size_t)b * CAP_C + i] = bx;
    sscore[(size_t)b * CAP_C + i] = sc;
  }
}

// Pairwise suppression masks: bit l of word w in row i <=> IoU(i, 64w+l) > 0.7.
// Pad rows (zero boxes) produce all-zero rows/columns (inter=0 -> iou=0).
__global__ void __launch_bounds__(256) mask_kernel(const float4* __restrict__ sboxes,
                                                   u64* __restrict__ mask) {
#pragma clang fp contract(off)
  __shared__ float4 sb[CAP_C];  // 32 KB
  int b = blockIdx.y, t = threadIdx.x;
  int wave = t >> 6, lane = t & 63;
  const float4* src = sboxes + (size_t)b * CAP_C;
  for (int i = t; i < CAP_C; i += 256) sb[i] = src[i];
  __syncthreads();
  for (int r = 0; r < MROWS; ++r) {
    int row = blockIdx.x * MROWS + r;
    float4 rb = sb[row];                       // broadcast read
    float ra = (rb.z - rb.x) * (rb.w - rb.y);  // picked-box area (barea)
    for (int chunk = wave; chunk < NW; chunk += 4) {
      float4 cb = sb[chunk * 64 + lane];
      float ix1 = fmaxf(rb.x, cb.x), iy1 = fmaxf(rb.y, cb.y);
      float ix2 = fminf(rb.z, cb.z), iy2 = fminf(rb.w, cb.w);
      float inter = fmaxf(ix2 - ix1, 0.0f) * fmaxf(iy2 - iy1, 0.0f);
      float ca = (cb.z - cb.x) * (cb.w - cb.y);
      float iou = inter / (ra + ca - inter + 1e-9f);
      u64 bal = __ballot(iou > 0.7f);
      if (lane == 0)
        mask[((size_t)b * CAP_C + row) * NW + chunk] = bal;
    }
  }
}

// ---- Walk v4: tile-resolve + apply, with ASM-FORCED register residency.
// Round-6 (v3): named C regs got folded (VGPR=76) and loads re-sank into the
// apply -> ~5300 cyc/tile of serialized latency groups. Fix: empty inline-asm
// with "+v" operands after the loads. Asm operands cannot be spilled or
// rematerialized -> all 64 row-words MUST be VGPR-resident before the resolve;
// one amortized vmcnt per tile. Double-buffered A/B (256 VGPRs; fits the
// (64,1) 512-reg budget): if the compiler emits partial vmcnt, next tile's
// loads overlap this tile's ~900cyc resolve; worst case it drains and we
// still get single-wait-per-tile.
// Lanes >= NW hold garbage in A/B/removed; consumed only via readlane(<NW).

#define X64(F) F(0) F(1) F(2) F(3) F(4) F(5) F(6) F(7) F(8) F(9) F(10) F(11) \
  F(12) F(13) F(14) F(15) F(16) F(17) F(18) F(19) F(20) F(21) F(22) F(23) \
  F(24) F(25) F(26) F(27) F(28) F(29) F(30) F(31) F(32) F(33) F(34) F(35) \
  F(36) F(37) F(38) F(39) F(40) F(41) F(42) F(43) F(44) F(45) F(46) F(47) \
  F(48) F(49) F(50) F(51) F(52) F(53) F(54) F(55) F(56) F(57) F(58) F(59) \
  F(60) F(61) F(62) F(63)

#define DCA(n) u64 A##n;
#define DCB(n) u64 B##n;
#define LDA(n) A##n = Mr[(size_t)(n) * NW];
#define LDB(n) B##n = Mr[(size_t)(n) * NW];
#define APA(n) acc |= A##n & ((u64)0 - ((keep >> (n)) & 1ull));
#define APB(n) acc |= B##n & ((u64)0 - ((keep >> (n)) & 1ull));

#define BAR16(p, a, b2, c, d, e, f, g, h, i, j, k, l, m, n2, o, q) \
  asm volatile("" : "+v"(p##a), "+v"(p##b2), "+v"(p##c), "+v"(p##d), \
                    "+v"(p##e), "+v"(p##f), "+v"(p##g), "+v"(p##h), \
                    "+v"(p##i), "+v"(p##j), "+v"(p##k), "+v"(p##l), \
                    "+v"(p##m), "+v"(p##n2), "+v"(p##o), "+v"(p##q));
#define BARRIER(p) \
  BAR16(p, 0, 1, 2, 3, 4, 5, 6, 7, 8, 9, 10, 11, 12, 13, 14, 15) \
  BAR16(p, 16, 17, 18, 19, 20, 21, 22, 23, 24, 25, 26, 27, 28, 29, 30, 31) \
  BAR16(p, 32, 33, 34, 35, 36, 37, 38, 39, 40, 41, 42, 43, 44, 45, 46, 47) \
  BAR16(p, 48, 49, 50, 51, 52, 53, 54, 55, 56, 57, 58, 59, 60, 61, 62, 63)

// Resolve tile at `base` (scalar wave-uniform loop over keeps; D = diagonal
// word, lane j = row j's within-tile suppression), record keeps, then apply
// buffer P's rows into `removed`.
#define TILE_STEP(P) { \
  unsigned tl = (unsigned)(base >> 6); \
  unsigned rlo = __builtin_amdgcn_readlane((unsigned)(removed & 0xFFFFFFFFull), tl); \
  unsigned rhi = __builtin_amdgcn_readlane((unsigned)(removed >> 32), tl); \
  u64 in_rm = ((u64)rhi << 32) | (u64)rlo; \
  int rem = cnt - base; \
  u64 valid = (rem >= 64) ? ~0ull : ((rem <= 0) ? 0ull : ((1ull << rem) - 1ull)); \
  u64 pend = (~in_rm) & valid; \
  u64 keep = 0ull; \
  int nk0 = nk; \
  while (pend != 0ull && nk < K) { \
    int j = __builtin_ctzll(pend); \
    keep |= (1ull << j); \
    ++nk; \
    unsigned dlo = __builtin_amdgcn_readlane((unsigned)(D & 0xFFFFFFFFull), j); \
    unsigned dhi = __builtin_amdgcn_readlane((unsigned)(D >> 32), j); \
    u64 row = ((u64)dhi << 32) | (u64)dlo; \
    pend &= ~row; \
    pend &= ~(1ull << j); \
  } \
  if ((keep >> lane) & 1ull) \
    s_keep[nk0 + __popcll(keep & ((1ull << lane) - 1ull))] = base + lane; \
  u64 acc = 0ull; \
  X64(AP##P) \
  removed |= acc; \
}

__global__ void __launch_bounds__(64, 1) walk_kernel(const u64* __restrict__ mask,
                                                     const float4* __restrict__ sboxes,
                                                     const float* __restrict__ sscore,
                                                     const unsigned* __restrict__ cntp,
                                                     float* __restrict__ out, int K) {
  __shared__ int s_keep[KMAX];
  const int b = blockIdx.x;
  const int lane = threadIdx.x;
  const u64* M = mask + (size_t)b * CAP_C * NW;
  int cnt = (int)cntp[b * CNT_STRIDE];
  if (cnt > CAP_C) cnt = CAP_C;
  u64 removed = 0ull;
  int nk = 0;
  X64(DCA)
  X64(DCB)
  u64 D = M[(size_t)lane * NW];  // tile-0 diagonal: lane j = M[j][0]
  u64 Dn;
  int base = 0;
  {
    const u64* Mr = M + lane;    // tile-0 rows
    X64(LDA)
  }
  for (int t = 0; t < CAP_C / 64; t += 2) {
    {
      int nt = (base + 64 < CAP_C) ? (base + 64) : base;
      const u64* Mr = M + (size_t)nt * NW + lane;
      X64(LDB)
      Dn = M[((size_t)nt + lane) * NW + (size_t)(nt >> 6)];
    }
    BARRIER(A)
    TILE_STEP(A)
    D = Dn; base += 64;
    if (base >= cnt || nk >= K) break;
    {
      int nt = (base + 64 < CAP_C) ? (base + 64) : base;
      const u64* Mr = M + (size_t)nt * NW + lane;
      X64(LDA)
      Dn = M[((size_t)nt + lane) * NW + (size_t)(nt >> 6)];
    }
    BARRIER(B)
    TILE_STEP(B)
    D = Dn; base += 64;
    if (base >= cnt || nk >= K) break;
  }
  __syncthreads();
  for (int j = lane; j < nk; j += 64) {
    int i = s_keep[j];
    float4 bx = sboxes[(size_t)b * CAP_C + i];
    float sc = sscore[(size_t)b * CAP_C + i];
    float* row = out + ((size_t)b * K + j) * 6;
    row[0] = bx.x; row[1] = bx.y; row[2] = bx.z; row[3] = bx.w;
    row[4] = sc; row[5] = 1.0f;
  }
  for (int j = nk + lane; j < K; j += 64) {  // zero invalid tail rows
    float* row = out + ((size_t)b * K + j) * 6;
    row[0] = 0.f; row[1] = 0.f; row[2] = 0.f; row[3] = 0.f;
    row[4] = 0.f; row[5] = 0.f;
  }
}

extern "C" void kernel_launch(void* const* d_in, const int* in_sizes, int n_in,
                              void* d_out, int out_size, void* d_ws, size_t ws_size,
                              hipStream_t stream) {
  const float4* anchors = (const float4*)d_in[0];
  const float4* deltas = (const float4*)d_in[1];
  const float* obj = (const float*)d_in[2];
  const int* imh = (const int*)d_in[3];
  const int* imw = (const int*)d_in[4];
  int N = in_sizes[0] / 4;
  int B = in_sizes[2] / N;
  int K = out_size / (B * 6);
  if (K > KMAX) K = KMAX;

  // ws layout (alignment-descending). NOTE: keys must follow mask (walk's
  // lanes>=NW over-read <=248B past a row; must stay inside ws).
  char* ws = (char*)d_ws;
  size_t off = 0;
  float4* boxes = (float4*)(ws + off);            off += (size_t)B * N * 16;
  float4* sboxes = (float4*)(ws + off);           off += (size_t)B * CAP_C * 16;
  u64* cand = (u64*)(ws + off);                   off += (size_t)B * CAP_C * 8;
  u64* mask = (u64*)(ws + off);                   off += (size_t)B * CAP_C * NW * 8;
  unsigned* keys = (unsigned*)(ws + off);         off += (size_t)B * N * 4;
  unsigned* hist = (unsigned*)(ws + off);         off += (size_t)B * NBINS * 4;
  float* sscore = (float*)(ws + off);             off += (size_t)B * CAP_C * 4;
  unsigned* T_lo = (unsigned*)(ws + off);         off += (size_t)B * 4;
  off = (off + 255) & ~(size_t)255;               // cnt on its own lines
  unsigned* cnt = (unsigned*)(ws + off);          off += (size_t)B * CNT_STRIDE * 4;
  float* out = (float*)d_out;

  int nb = (N + 255) / 256;
  int P = (N + HE - 1) / HE;
  decode_kernel<<<nb, 256, 0, stream>>>(anchors, deltas, obj, imh, imw,
                                        boxes, keys, hist, N, B);
  hist_kernel<<<dim3(P, 2, B), HB, 0, stream>>>(keys, hist, N);
  threshold_kernel<<<B, 256, 0, stream>>>(hist, T_lo, cnt);
  compact_kernel<<<dim3(CPB, B), 1024, 0, stream>>>(keys, T_lo, cand, cnt, N);
  sort_kernel<<<B, 1024, 0, stream>>>(cand, cnt, boxes, sboxes, sscore, N);
  mask_kernel<<<dim3(CAP_C / MROWS, B), 256, 0, stream>>>(sboxes, mask);
  walk_kernel<<<B, 64, 0, stream>>>(mask, sboxes, sscore, cnt, out, K);
}

// Round 8
// 203.736 us; speedup vs baseline: 6.6575x; 1.2030x over previous
//
#include <hip/hip_runtime.h>
#include <cstdint>
#include <cstddef>

#define NBINS 65536         // 16-bit histogram of orderable score
#define CAP_C 2048          // candidate pool (pow2, = sort size)
#define NW (CAP_C / 64)     // 64-bit mask words per row = 32
#define TARGET 1792u        // threshold target (headroom to CAP_C)
#define KMAX 1008           // kept-list capacity
#define MROWS 16            // rows per mask block
#define HB 1024             // hist block threads
#define HE 32768            // keys per hist block (16-bit pack: counts <= HE < 65536)
#define CNT_STRIDE 64       // cnt[b*64]: 256B per counter, no shared lines
#define CPB 64              // compact blocks per batch

typedef unsigned long long u64;

__device__ __forceinline__ unsigned orderable(float f) {
  unsigned b = __float_as_uint(f);
  return (b & 0x80000000u) ? ~b : (b | 0x80000000u);
}

// Pure streaming: also zero-fills hist (no separate init dispatch).
__global__ void decode_kernel(const float4* __restrict__ anchors,
                              const float4* __restrict__ deltas,
                              const float* __restrict__ obj,
                              const int* __restrict__ im_h_p,
                              const int* __restrict__ im_w_p,
                              float4* __restrict__ boxes,
                              unsigned* __restrict__ keys,
                              unsigned* __restrict__ hist,
                              int N, int B) {
#pragma clang fp contract(off)
  int n = blockIdx.x * blockDim.x + threadIdx.x;
  int stride = gridDim.x * blockDim.x;
  for (int j = n; j < B * NBINS; j += stride) hist[j] = 0u;
  if (n >= N) return;
  float imw = (float)(*im_w_p);
  float imh = (float)(*im_h_p);
  float4 a = anchors[n];
  float aw = a.z - a.x;
  float ah = a.w - a.y;
  float acx = a.x + 0.5f * aw;
  float acy = a.y + 0.5f * ah;
  const float LOGM = 4.135166556742356f;  // log(1000/16) rounded to f32
  for (int b = 0; b < B; ++b) {
    size_t off = (size_t)b * N + n;
    float4 d = deltas[off];
    float dw = fminf(d.z, LOGM), dh = fminf(d.w, LOGM);
    float pcx = d.x * aw + acx;
    float pcy = d.y * ah + acy;
    float pw = expf(dw) * aw;
    float ph = expf(dh) * ah;
    float x1 = fminf(fmaxf(pcx - 0.5f * pw, 0.0f), imw);
    float y1 = fminf(fmaxf(pcy - 0.5f * ph, 0.0f), imh);
    float x2 = fminf(fmaxf(pcx + 0.5f * pw, 0.0f), imw);
    float y2 = fminf(fmaxf(pcy + 0.5f * ph, 0.0f), imh);
    boxes[off] = make_float4(x1, y1, x2, y2);
    float area = (x2 - x1) * (y2 - y1);
    float sc = (area > 1.0f) ? obj[off] : -__builtin_inff();
    keys[off] = orderable(sc);
  }
}

// LDS-privatized histogram (round-4 win: killed 140us of contended atomics).
__global__ void __launch_bounds__(HB) hist_kernel(const unsigned* __restrict__ keys,
                                                  unsigned* __restrict__ hist,
                                                  int N) {
  __shared__ unsigned hl[NBINS / 4];  // 16384 uints = 64 KB
  int t = threadIdx.x;
  int half = blockIdx.y, b = blockIdx.z;
  unsigned lo_bin = (unsigned)half * 32768u;
  for (int i = t; i < NBINS / 4; i += HB) hl[i] = 0u;
  __syncthreads();
  const unsigned* kb = keys + (size_t)b * N;
  int base = blockIdx.x * HE;
  int end = base + HE;
  if (end > N) end = N;
  for (int i = base + t; i < end; i += HB) {
    unsigned bin = kb[i] >> 16;
    unsigned lb = bin - lo_bin;
    if (lb < 32768u)
      atomicAdd(&hl[lb >> 1], (lb & 1u) ? 65536u : 1u);
  }
  __syncthreads();
  unsigned* hg = hist + (size_t)b * NBINS + lo_bin;
  for (int i = t; i < NBINS / 4; i += HB) {
    unsigned v = hl[i];
    unsigned clo = v & 0xFFFFu, chi = v >> 16;
    if (clo) atomicAdd(&hg[2 * i], clo);
    if (chi) atomicAdd(&hg[2 * i + 1], chi);
  }
}

// One block per batch: pick bin threshold so [T_lo, NBINS) holds ~TARGET
// candidates (<= CAP_C). Also zeroes cnt[b*CNT_STRIDE] for compact.
__global__ void __launch_bounds__(256) threshold_kernel(const unsigned* __restrict__ hist,
                                                        unsigned* __restrict__ T_lo,
                                                        unsigned* __restrict__ cnt) {
  const int BPT = NBINS / 256;  // 256 bins/thread, contiguous ownership
  __shared__ unsigned s_part[256];
  __shared__ unsigned s_T;
  int b = blockIdx.x, t = threadIdx.x;
  const unsigned* h = hist + (size_t)b * NBINS;
  if (t == 0) { s_T = 0xFFFFFFFFu; cnt[b * CNT_STRIDE] = 0u; }
  unsigned mysum = 0;
  const uint4* h4 = (const uint4*)(h + t * BPT);
  for (int k = 0; k < BPT / 4; ++k) {
    int bin0 = t * BPT + k * 4;
    if (bin0 >= 128) {  // bin>=128 <=> finite score; 128 % 4 == 0
      uint4 v = h4[k];
      mysum += v.x + v.y + v.z + v.w;
    }
  }
  s_part[t] = mysum;
  __syncthreads();
  for (int d = 1; d < 256; d <<= 1) {  // inclusive suffix sum
    unsigned v = (t + d < 256) ? s_part[t + d] : 0u;
    __syncthreads();
    s_part[t] += v;
    __syncthreads();
  }
  unsigned total = s_part[0];
  unsigned target = (TARGET < total) ? TARGET : total;
  unsigned above = (t + 1 < 256) ? s_part[t + 1] : 0u;
  if (total > 0u && above < target && s_part[t] >= target) {  // unique crossing thread
    unsigned c = above;
    for (int k = BPT - 1; k >= 0; --k) {
      unsigned bin = (unsigned)(t * BPT + k);
      if (bin < 128u) break;
      unsigned hv = h[bin];
      c += hv;
      if (c >= target) {
        unsigned T = bin;
        if (c > CAP_C && (c - hv) > 0u) T = bin + 1u;  // never overflow CAP_C
        s_T = T;
        break;
      }
    }
  }
  __syncthreads();
  if (t == 0) T_lo[b] = (total == 0u) ? 0xFFFFFFFFu : s_T;
}

// compact v2: block-aggregated reservation (round-7 win: one atomic/block,
// cnt on private 256B line -> killed 70us of L2 line-ownership ping-pong).
__global__ void __launch_bounds__(1024) compact_kernel(const unsigned* __restrict__ keys,
                                                       const unsigned* __restrict__ T_lo,
                                                       u64* __restrict__ cand,
                                                       unsigned* __restrict__ cnt, int N) {
  __shared__ u64 s_w[4096];  // 32 KB winner staging (total/batch <= ~2048)
  __shared__ unsigned s_n, s_base;
  int b = blockIdx.y, t = threadIdx.x;
  if (t == 0) s_n = 0u;
  __syncthreads();
  unsigned T = T_lo[b];
  int slice = (N + CPB - 1) / CPB;
  int base = blockIdx.x * slice;
  int end = base + slice;
  if (end > N) end = N;
  const unsigned* kb = keys + (size_t)b * N;
  for (int i = base + t; i < end; i += 1024) {
    unsigned u = kb[i];
    if ((u >> 16) >= T) {
      unsigned p = atomicAdd(&s_n, 1u);
      if (p < 4096u)  // ~i: argmax lowest-index tie-break after descending sort
        s_w[p] = ((u64)u << 32) | (unsigned)(~i);
    }
  }
  __syncthreads();
  unsigned n = s_n < 4096u ? s_n : 4096u;
  if (t == 0) s_base = (n > 0u) ? atomicAdd(&cnt[b * CNT_STRIDE], n) : 0u;
  __syncthreads();
  unsigned gb = s_base;
  for (unsigned j = t; j < n; j += 1024) {
    unsigned p = gb + j;
    if (p < CAP_C) cand[(size_t)b * CAP_C + p] = s_w[j];
  }
}

// One block per batch: bitonic sort CAP_C keys descending, gather sorted boxes.
__global__ void __launch_bounds__(1024) sort_kernel(const u64* __restrict__ cand,
                                                    const unsigned* __restrict__ cntp,
                                                    const float4* __restrict__ boxes,
                                                    float4* __restrict__ sboxes,
                                                    float* __restrict__ sscore,
                                                    int N) {
  __shared__ u64 sk[CAP_C];  // 16 KB
  int b = blockIdx.x, t = threadIdx.x;
  int cnt = (int)cntp[b * CNT_STRIDE];
  if (cnt > CAP_C) cnt = CAP_C;
  for (int i = t; i < CAP_C; i += 1024)
    sk[i] = (i < cnt) ? cand[(size_t)b * CAP_C + i] : 0ull;  // pad sinks to end
  __syncthreads();
  for (unsigned kk = 2; kk <= CAP_C; kk <<= 1) {
    for (unsigned j = kk >> 1; j >= 1u; j >>= 1) {
      unsigned pid = (unsigned)t;  // exactly CAP_C/2 pairs
      unsigned i = ((pid & ~(j - 1u)) << 1) | (pid & (j - 1u));
      unsigned p = i | j;
      u64 va = sk[i], vb = sk[p];
      bool up = ((i & kk) == 0u);
      bool sw = up ? (va < vb) : (va > vb);
      if (sw) { sk[i] = vb; sk[p] = va; }
      __syncthreads();
    }
  }
  for (int i = t; i < CAP_C; i += 1024) {
    u64 key = sk[i];
    float4 bx = make_float4(0.f, 0.f, 0.f, 0.f);
    float sc = -__builtin_inff();
    if (i < cnt) {
      unsigned idx = ~(unsigned)(key & 0xFFFFFFFFull);
      bx = boxes[(size_t)b * N + idx];
      unsigned u = (unsigned)(key >> 32);
      unsigned sb2 = (u & 0x80000000u) ? (u ^ 0x80000000u) : ~u;
      sc = __uint_as_float(sb2);
    }
    sboxes[(size_t)b * CAP_C + i] = bx;
    sscore[(size_t)b * CAP_C + i] = sc;
  }
}

// Pairwise suppression masks: bit l of word w in row i <=> IoU(i, 64w+l) > 0.7.
// Diagonal bit i of row i IS set (IoU(i,i)=a/(a+1e-9)>0.7 for area>1 cands).
__global__ void __launch_bounds__(256) mask_kernel(const float4* __restrict__ sboxes,
                                                   u64* __restrict__ mask) {
#pragma clang fp contract(off)
  __shared__ float4 sb[CAP_C];  // 32 KB
  int b = blockIdx.y, t = threadIdx.x;
  int wave = t >> 6, lane = t & 63;
  const float4* src = sboxes + (size_t)b * CAP_C;
  for (int i = t; i < CAP_C; i += 256) sb[i] = src[i];
  __syncthreads();
  for (int r = 0; r < MROWS; ++r) {
    int row = blockIdx.x * MROWS + r;
    float4 rb = sb[row];                       // broadcast read
    float ra = (rb.z - rb.x) * (rb.w - rb.y);  // picked-box area (barea)
    for (int chunk = wave; chunk < NW; chunk += 4) {
      float4 cb = sb[chunk * 64 + lane];
      float ix1 = fmaxf(rb.x, cb.x), iy1 = fmaxf(rb.y, cb.y);
      float ix2 = fminf(rb.z, cb.z), iy2 = fminf(rb.w, cb.w);
      float inter = fmaxf(ix2 - ix1, 0.0f) * fmaxf(iy2 - iy1, 0.0f);
      float ca = (cb.z - cb.x) * (cb.w - cb.y);
      float iou = inter / (ra + ca - inter + 1e-9f);
      u64 bal = __ballot(iou > 0.7f);
      if (lane == 0)
        mask[((size_t)b * CAP_C + row) * NW + chunk] = bal;
    }
  }
}

// ---- Walk v5: O(#suppressions) resolve via ballot-find-first-suppressor.
// Round-7 lesson: the per-KEEP scalar loop (ctz -> 2x dynamic readlane ->
// branch, ~1000 serial trips x ~100cyc) was the 67us floor, not memory.
// New resolve: lane j sets cond = pend[j] && (D_j & pend & bits>j) != 0.
//   ballot==0  => keep = pend (one shot; symmetric matrix => no hidden
//                 suppressor can exist below the first cond lane).
//   else f=ctz => all pendings <= f kept, apply row f, repeat.
// Trips = #keeps whose row intersects remaining pend (~2/tile here).
// K-cutoff: greedy order within a tile == ascending index, so trimming keep
// to its first (K-nk) set bits is exact; re-ballot makes it uniform.
// Memory structure (A/B reg buffers + "+v" asm pin) unchanged from v4.

#define X64(F) F(0) F(1) F(2) F(3) F(4) F(5) F(6) F(7) F(8) F(9) F(10) F(11) \
  F(12) F(13) F(14) F(15) F(16) F(17) F(18) F(19) F(20) F(21) F(22) F(23) \
  F(24) F(25) F(26) F(27) F(28) F(29) F(30) F(31) F(32) F(33) F(34) F(35) \
  F(36) F(37) F(38) F(39) F(40) F(41) F(42) F(43) F(44) F(45) F(46) F(47) \
  F(48) F(49) F(50) F(51) F(52) F(53) F(54) F(55) F(56) F(57) F(58) F(59) \
  F(60) F(61) F(62) F(63)

#define DCA(n) u64 A##n;
#define DCB(n) u64 B##n;
#define LDA(n) A##n = Mr[(size_t)(n) * NW];
#define LDB(n) B##n = Mr[(size_t)(n) * NW];
#define APA(n) acc |= A##n & ((u64)0 - ((keep >> (n)) & 1ull));
#define APB(n) acc |= B##n & ((u64)0 - ((keep >> (n)) & 1ull));

#define BAR16(p, a, b2, c, d, e, f, g, h, i, j, k, l, m, n2, o, q) \
  asm volatile("" : "+v"(p##a), "+v"(p##b2), "+v"(p##c), "+v"(p##d), \
                    "+v"(p##e), "+v"(p##f), "+v"(p##g), "+v"(p##h), \
                    "+v"(p##i), "+v"(p##j), "+v"(p##k), "+v"(p##l), \
                    "+v"(p##m), "+v"(p##n2), "+v"(p##o), "+v"(p##q));
#define BARRIER(p) \
  BAR16(p, 0, 1, 2, 3, 4, 5, 6, 7, 8, 9, 10, 11, 12, 13, 14, 15) \
  BAR16(p, 16, 17, 18, 19, 20, 21, 22, 23, 24, 25, 26, 27, 28, 29, 30, 31) \
  BAR16(p, 32, 33, 34, 35, 36, 37, 38, 39, 40, 41, 42, 43, 44, 45, 46, 47) \
  BAR16(p, 48, 49, 50, 51, 52, 53, 54, 55, 56, 57, 58, 59, 60, 61, 62, 63)

#define TILE_STEP(P) { \
  unsigned tl = (unsigned)(base >> 6); \
  unsigned rlo = __builtin_amdgcn_readlane((unsigned)(removed & 0xFFFFFFFFull), tl); \
  unsigned rhi = __builtin_amdgcn_readlane((unsigned)(removed >> 32), tl); \
  u64 in_rm = ((u64)rhi << 32) | (u64)rlo; \
  int rem = cnt - base; \
  u64 valid = (rem >= 64) ? ~0ull : ((rem <= 0) ? 0ull : ((1ull << rem) - 1ull)); \
  u64 pend = (~in_rm) & valid; \
  u64 keep = 0ull; \
  while (pend != 0ull) { \
    bool cond = ((pend >> lane) & 1ull) && ((D & pend & lane_above) != 0ull); \
    u64 bal = __ballot((int)cond); \
    if (bal == 0ull) { keep |= pend; break; } \
    int f = __builtin_ctzll(bal); \
    u64 beq = (2ull << f) - 1ull;            /* bits <= f (f=63 wraps to ~0) */ \
    keep |= pend & beq; \
    unsigned dlo = __builtin_amdgcn_readlane((unsigned)(D & 0xFFFFFFFFull), f); \
    unsigned dhi = __builtin_amdgcn_readlane((unsigned)(D >> 32), f); \
    u64 rowf = ((u64)dhi << 32) | (u64)dlo; \
    pend &= ~beq; \
    pend &= ~rowf; \
  } \
  int cap = K - nk; \
  int kc = __popcll(keep); \
  if (kc > cap) {                            /* exact greedy K-cutoff */ \
    bool mine = ((keep >> lane) & 1ull) && \
                (__popcll(keep & ((1ull << lane) - 1ull)) < cap); \
    keep = __ballot((int)mine); \
    kc = cap; \
  } \
  if ((keep >> lane) & 1ull) \
    s_keep[nk + __popcll(keep & ((1ull << lane) - 1ull))] = base + lane; \
  nk += kc; \
  u64 acc = 0ull; \
  X64(AP##P) \
  removed |= acc; \
}

__global__ void __launch_bounds__(64, 1) walk_kernel(const u64* __restrict__ mask,
                                                     const float4* __restrict__ sboxes,
                                                     const float* __restrict__ sscore,
                                                     const unsigned* __restrict__ cntp,
                                                     float* __restrict__ out, int K) {
  __shared__ int s_keep[KMAX];
  const int b = blockIdx.x;
  const int lane = threadIdx.x;
  const u64* M = mask + (size_t)b * CAP_C * NW;
  int cnt = (int)cntp[b * CNT_STRIDE];
  if (cnt > CAP_C) cnt = CAP_C;
  const u64 lane_above = (lane == 63) ? 0ull : (~0ull << (lane + 1));
  u64 removed = 0ull;
  int nk = 0;
  X64(DCA)
  X64(DCB)
  u64 D = M[(size_t)lane * NW];  // tile-0 diagonal: lane j = M[j][0]
  u64 Dn;
  int base = 0;
  {
    const u64* Mr = M + lane;    // tile-0 rows
    X64(LDA)
  }
  for (int t = 0; t < CAP_C / 64; t += 2) {
    {
      int nt = (base + 64 < CAP_C) ? (base + 64) : base;
      const u64* Mr = M + (size_t)nt * NW + lane;
      X64(LDB)
      Dn = M[((size_t)nt + lane) * NW + (size_t)(nt >> 6)];
    }
    BARRIER(A)
    TILE_STEP(A)
    D = Dn; base += 64;
    if (base >= cnt || nk >= K) break;
    {
      int nt = (base + 64 < CAP_C) ? (base + 64) : base;
      const u64* Mr = M + (size_t)nt * NW + lane;
      X64(LDA)
      Dn = M[((size_t)nt + lane) * NW + (size_t)(nt >> 6)];
    }
    BARRIER(B)
    TILE_STEP(B)
    D = Dn; base += 64;
    if (base >= cnt || nk >= K) break;
  }
  __syncthreads();
  for (int j = lane; j < nk; j += 64) {
    int i = s_keep[j];
    float4 bx = sboxes[(size_t)b * CAP_C + i];
    float sc = sscore[(size_t)b * CAP_C + i];
    float* row = out + ((size_t)b * K + j) * 6;
    row[0] = bx.x; row[1] = bx.y; row[2] = bx.z; row[3] = bx.w;
    row[4] = sc; row[5] = 1.0f;
  }
  for (int j = nk + lane; j < K; j += 64) {  // zero invalid tail rows
    float* row = out + ((size_t)b * K + j) * 6;
    row[0] = 0.f; row[1] = 0.f; row[2] = 0.f; row[3] = 0.f;
    row[4] = 0.f; row[5] = 0.f;
  }
}

extern "C" void kernel_launch(void* const* d_in, const int* in_sizes, int n_in,
                              void* d_out, int out_size, void* d_ws, size_t ws_size,
                              hipStream_t stream) {
  const float4* anchors = (const float4*)d_in[0];
  const float4* deltas = (const float4*)d_in[1];
  const float* obj = (const float*)d_in[2];
  const int* imh = (const int*)d_in[3];
  const int* imw = (const int*)d_in[4];
  int N = in_sizes[0] / 4;
  int B = in_sizes[2] / N;
  int K = out_size / (B * 6);
  if (K > KMAX) K = KMAX;

  // ws layout (alignment-descending). NOTE: keys must follow mask (walk's
  // lanes>=NW over-read <=248B past a row; must stay inside ws).
  char* ws = (char*)d_ws;
  size_t off = 0;
  float4* boxes = (float4*)(ws + off);            off += (size_t)B * N * 16;
  float4* sboxes = (float4*)(ws + off);           off += (size_t)B * CAP_C * 16;
  u64* cand = (u64*)(ws + off);                   off += (size_t)B * CAP_C * 8;
  u64* mask = (u64*)(ws + off);                   off += (size_t)B * CAP_C * NW * 8;
  unsigned* keys = (unsigned*)(ws + off);         off += (size_t)B * N * 4;
  unsigned* hist = (unsigned*)(ws + off);         off += (size_t)B * NBINS * 4;
  float* sscore = (float*)(ws + off);             off += (size_t)B * CAP_C * 4;
  unsigned* T_lo = (unsigned*)(ws + off);         off += (size_t)B * 4;
  off = (off + 255) & ~(size_t)255;               // cnt on its own lines
  unsigned* cnt = (unsigned*)(ws + off);          off += (size_t)B * CNT_STRIDE * 4;
  float* out = (float*)d_out;

  int nb = (N + 255) / 256;
  int P = (N + HE - 1) / HE;
  decode_kernel<<<nb, 256, 0, stream>>>(anchors, deltas, obj, imh, imw,
                                        boxes, keys, hist, N, B);
  hist_kernel<<<dim3(P, 2, B), HB, 0, stream>>>(keys, hist, N);
  threshold_kernel<<<B, 256, 0, stream>>>(hist, T_lo, cnt);
  compact_kernel<<<dim3(CPB, B), 1024, 0, stream>>>(keys, T_lo, cand, cnt, N);
  sort_kernel<<<B, 1024, 0, stream>>>(cand, cnt, boxes, sboxes, sscore, N);
  mask_kernel<<<dim3(CAP_C / MROWS, B), 256, 0, stream>>>(sboxes, mask);
  walk_kernel<<<B, 64, 0, stream>>>(mask, sboxes, sscore, cnt, out, K);
}